// Round 12
// baseline (479.353 us; speedup 1.0000x reference)
//
#include <hip/hip_runtime.h>
#include <hip/hip_bf16.h>

typedef __hip_bfloat16 bf16;
typedef __attribute__((ext_vector_type(8))) short short8;
typedef __attribute__((ext_vector_type(4))) float f32x4;

static __device__ __forceinline__ float b2f(bf16 v) { return __bfloat162float(v); }

// flag-aware input load: bf==1 -> bf16, bf==0 -> f32
static __device__ __forceinline__ float ldin(const void* p, long i, int bf) {
    return bf ? b2f(((const bf16*)p)[i]) : ((const float*)p)[i];
}

// ---------------- dtype detect ----------------
__global__ void detect_k(const unsigned short* __restrict__ x16, int* __restrict__ flag) {
    __shared__ int cnt[256];
    unsigned short u = x16[threadIdx.x];
    int e = (u >> 7) & 0xFF;
    cnt[threadIdx.x] = (e >= 100 && e <= 140) ? 1 : 0;
    __syncthreads();
    for (int off = 128; off > 0; off >>= 1) {
        if (threadIdx.x < off) cnt[threadIdx.x] += cnt[threadIdx.x + off];
        __syncthreads();
    }
    if (threadIdx.x == 0) *flag = (cnt[0] > 217) ? 1 : 0;
}

// ---------------- transposes ----------------
__global__ void transpose_w_k(const void* __restrict__ in, float* __restrict__ out,
                              int M, int K, const int* __restrict__ flagp) {
    int bf = *flagp;
    int idx = blockIdx.x * 256 + threadIdx.x;
    if (idx >= M * K) return;
    int k = idx / M, m = idx - k * M;
    out[idx] = ldin(in, (long)m * K + k, bf);
}

// w3b[n][h3][c] (bf16) from w3[(h3*256+c)*32+n]
__global__ __launch_bounds__(256) void transpose_w3b_k(const void* __restrict__ w3,
                                                       bf16* __restrict__ out,
                                                       const int* __restrict__ flagp) {
    int bf = *flagp;
    int h3 = blockIdx.x;     // 512
    __shared__ bf16 t[8192];
    long base = (long)h3 * 8192;
    for (int i = threadIdx.x; i < 8192; i += 256)
        t[i] = __float2bfloat16(ldin(w3, base + i, bf));   // exact when input is bf16
    __syncthreads();
    for (int i = threadIdx.x; i < 8192; i += 256) {
        int n = i >> 8, c = i & 255;
        out[((long)n * 512 + h3) * 256 + c] = t[c * 32 + n];
    }
}

// hbT[b][tau][c] (bf16) from h[b][c][tau] (fp32)
__global__ void cast_hT_k(const float* __restrict__ h, bf16* __restrict__ out) {
    int idx = blockIdx.x * 256 + threadIdx.x;   // 131072
    if (idx >= 131072) return;
    int b = idx >> 16, r = idx & 65535;
    int tau = r >> 8, c = r & 255;
    out[idx] = __float2bfloat16(h[b * 65536 + c * 256 + tau]);
}

// ---------------- im2col ----------------
__global__ void im2col_x_k(const void* __restrict__ x, float* __restrict__ colx,
                           const int* __restrict__ flagp) {
    int bf = *flagp;
    int idx = blockIdx.x * 256 + threadIdx.x;   // 786432
    if (idx >= 786432) return;
    int t = idx & 255;
    int b = idx / 393216;
    int k = (idx - b * 393216) >> 8;
    int c = k / 3, q = k - c * 3;
    int tt = t + q - 1;
    colx[idx] = (tt >= 0 && tt < 256) ? ldin(x, ((long)b * 512 + c) * 256 + tt, bf) : 0.f;
}

__global__ void im2col_f_k(const float* __restrict__ f, float* __restrict__ col) {
    int idx = blockIdx.x * 256 + threadIdx.x;   // 4718592
    if (idx >= 4718592) return;
    int p = idx & 2047;
    int rem = idx >> 11;
    int b = rem / 1152;
    int k = rem - b * 1152;
    int c = k / 9, q = k - c * 9;
    int dy = q / 3, dx = q - dy * 3;
    int t = p >> 3, w = p & 7;
    int tt = t + dy - 1, ww = w + dx - 1;
    col[idx] = (tt >= 0 && tt < 256 && ww >= 0 && ww < 8)
                   ? f[((long)b * 128 + c) * 2048 + tt * 8 + ww] : 0.f;
}

// ---------------- MFMA P-GEMM ----------------
// P[b, h3, n, tau] = sum_c w3[h3,c,n] * h[b,c,tau]   (bf16 x bf16 -> fp32)
__global__ __launch_bounds__(256) void pgemm_mfma(
    const bf16* __restrict__ w3b, const bf16* __restrict__ hbT,
    float* __restrict__ P)
{
    int z = blockIdx.z;          // b*32 + n
    int b = z >> 5, n = z & 31;
    int bm = blockIdx.y;         // 0..7 (h3 64-strip)
    int tid = threadIdx.x;
    int wv = tid >> 6, lane = tid & 63;
    int q = lane >> 4, col = lane & 15;

    f32x4 acc[16];
    #pragma unroll
    for (int i = 0; i < 16; ++i) acc[i] = (f32x4){0.f, 0.f, 0.f, 0.f};

    const short8* Abase = (const short8*)(w3b + ((long)n * 512 + bm * 64 + wv * 16 + col) * 256);
    const short8* Bbase = (const short8*)(hbT + (long)b * 65536);

    #pragma unroll
    for (int kc = 0; kc < 8; ++kc) {
        short8 af = Abase[kc * 4 + q];
        #pragma unroll
        for (int nt = 0; nt < 16; ++nt) {
            short8 bfr = Bbase[(nt * 16 + col) * 32 + kc * 4 + q];
            acc[nt] = __builtin_amdgcn_mfma_f32_16x16x32_bf16(af, bfr, acc[nt], 0, 0, 0);
        }
    }

    long dbase = (long)b * 4194304 + (long)n * 256 +
                 (long)(bm * 64 + wv * 16 + q * 4) * 8192 + col;
    #pragma unroll
    for (int nt = 0; nt < 16; ++nt)
        #pragma unroll
        for (int r = 0; r < 4; ++r)
            P[dbase + (long)r * 8192 + nt * 16] = acc[nt][r];
}

// ---------------- generic tiled GEMM w/ register prefetch (64x64, 4x4) ----------------
template<int BM, int BP, int TM, int TP>
__global__ __launch_bounds__(256) void gemm_t(
    const float* __restrict__ A, const float* __restrict__ B, float* __restrict__ C,
    const void* __restrict__ bias, const void* __restrict__ bias2,
    int M, int K, int P, int az_mod, int bz_div,
    long a_zs, long b_zs, long c_zs1, long c_zs2, int c_ms,
    int zmod, int ksplit, long sstride, int accum, const int* __restrict__ flagp)
{
    int bf = *flagp;
    int zraw = blockIdx.z;
    int z = zraw % zmod;
    int ks = zraw / zmod;
    int klen = K / ksplit;
    int kbeg = ks * klen;
    int kend = kbeg + klen;
    int za = z % az_mod;
    const float* A2 = A + (long)za * a_zs;
    const float* B2 = B + (long)(z / bz_div) * b_zs;
    float* C2 = C + (long)(z / bz_div) * c_zs1 + (long)za * c_zs2;
    const void* bi = (bias2 != nullptr && za != 0) ? bias2 : bias;

    __shared__ float As[16][BM];
    __shared__ float Bs[16][BP];
    int tid = threadIdx.x;
    int ty = tid >> 4, tx = tid & 15;
    int lk = tid >> 4;
    int lma = (tid & 15) * TM;
    int lpb = (tid & 15) * TP;
    int m0 = blockIdx.y * BM, p0 = blockIdx.x * BP;

    float acc[TM][TP];
    #pragma unroll
    for (int i = 0; i < TM; ++i)
        #pragma unroll
        for (int j = 0; j < TP; ++j) acc[i][j] = 0.f;

    float ra[TM], rb[TP];
    {
        const float* ap = A2 + (long)(kbeg + lk) * M + m0 + lma;
        const float* bp = B2 + (long)(kbeg + lk) * P + p0 + lpb;
        #pragma unroll
        for (int u = 0; u < TM; ++u) ra[u] = ap[u];
        #pragma unroll
        for (int u = 0; u < TP; ++u) rb[u] = bp[u];
    }

    for (int kc = kbeg; kc < kend; kc += 16) {
        #pragma unroll
        for (int u = 0; u < TM; ++u) As[lk][lma + u] = ra[u];
        #pragma unroll
        for (int u = 0; u < TP; ++u) Bs[lk][lpb + u] = rb[u];
        __syncthreads();
        if (kc + 16 < kend) {
            const float* ap = A2 + (long)(kc + 16 + lk) * M + m0 + lma;
            const float* bp = B2 + (long)(kc + 16 + lk) * P + p0 + lpb;
            #pragma unroll
            for (int u = 0; u < TM; ++u) ra[u] = ap[u];
            #pragma unroll
            for (int u = 0; u < TP; ++u) rb[u] = bp[u];
        }
        #pragma unroll
        for (int kk = 0; kk < 16; ++kk) {
            float av[TM], bv[TP];
            #pragma unroll
            for (int i = 0; i < TM; ++i) av[i] = As[kk][ty * TM + i];
            #pragma unroll
            for (int j = 0; j < TP; ++j) bv[j] = Bs[kk][tx * TP + j];
            #pragma unroll
            for (int i = 0; i < TM; ++i)
                #pragma unroll
                for (int j = 0; j < TP; ++j)
                    acc[i][j] += av[i] * bv[j];
        }
        __syncthreads();
    }

    #pragma unroll
    for (int i = 0; i < TM; ++i) {
        int m = m0 + ty * TM + i;
        float bb = bi ? ldin(bi, m, bf) : 0.f;
        #pragma unroll
        for (int j = 0; j < TP; ++j) {
            long idx = (long)m * c_ms + p0 + tx * TP + j;
            if (accum == 1) C2[sstride * ks + idx] = acc[i][j];
            else if (accum == 2) C2[idx] += acc[i][j];
            else C2[idx] = acc[i][j] + bb;
        }
    }
}

// ---------------- 128x128 quad GEMM: 8x8/thread as 2x2 quadrants of 4x4 ----------------
__global__ __launch_bounds__(256) void gemm_q(
    const float* __restrict__ A, const float* __restrict__ B, float* __restrict__ C,
    const void* __restrict__ bias, const void* __restrict__ bias2,
    int M, int K, int P, int az_mod, int bz_div,
    long a_zs, long b_zs, long c_zs1, long c_zs2, int c_ms,
    int zmod, int ksplit, long sstride, int accum, const int* __restrict__ flagp)
{
    int bf = *flagp;
    int zraw = blockIdx.z;
    int z = zraw % zmod;
    int ks = zraw / zmod;
    int klen = K / ksplit;
    int kbeg = ks * klen, kend = kbeg + klen;
    int za = z % az_mod;
    const float* A2 = A + (long)za * a_zs;
    const float* B2 = B + (long)(z / bz_div) * b_zs;
    float* C2 = C + (long)(z / bz_div) * c_zs1 + (long)za * c_zs2;
    const void* bi = (bias2 != nullptr && za != 0) ? bias2 : bias;

    __shared__ float As[16][128];
    __shared__ float Bs[16][128];
    int tid = threadIdx.x;
    int ty = tid >> 4, tx = tid & 15;
    int lk = tid >> 4;
    int lc4 = (tid & 15) * 4;
    int m0 = blockIdx.y * 128, p0 = blockIdx.x * 128;

    float acc[8][8];
    #pragma unroll
    for (int i = 0; i < 8; ++i)
        #pragma unroll
        for (int j = 0; j < 8; ++j) acc[i][j] = 0.f;

    float4 ra0, ra1, rb0, rb1;
    {
        const float* ap = A2 + (long)(kbeg + lk) * M + m0 + lc4;
        const float* bp = B2 + (long)(kbeg + lk) * P + p0 + lc4;
        ra0 = *(const float4*)ap;  ra1 = *(const float4*)(ap + 64);
        rb0 = *(const float4*)bp;  rb1 = *(const float4*)(bp + 64);
    }

    for (int kc = kbeg; kc < kend; kc += 16) {
        *(float4*)&As[lk][lc4]      = ra0;
        *(float4*)&As[lk][64 + lc4] = ra1;
        *(float4*)&Bs[lk][lc4]      = rb0;
        *(float4*)&Bs[lk][64 + lc4] = rb1;
        __syncthreads();
        if (kc + 16 < kend) {
            const float* ap = A2 + (long)(kc + 16 + lk) * M + m0 + lc4;
            const float* bp = B2 + (long)(kc + 16 + lk) * P + p0 + lc4;
            ra0 = *(const float4*)ap;  ra1 = *(const float4*)(ap + 64);
            rb0 = *(const float4*)bp;  rb1 = *(const float4*)(bp + 64);
        }
        #pragma unroll
        for (int kk = 0; kk < 16; ++kk) {
            float4 av0 = *(float4*)&As[kk][ty * 4];
            float4 av1 = *(float4*)&As[kk][64 + ty * 4];
            float4 bv0 = *(float4*)&Bs[kk][tx * 4];
            float4 bv1 = *(float4*)&Bs[kk][64 + tx * 4];
            float av[8] = {av0.x, av0.y, av0.z, av0.w, av1.x, av1.y, av1.z, av1.w};
            float bv[8] = {bv0.x, bv0.y, bv0.z, bv0.w, bv1.x, bv1.y, bv1.z, bv1.w};
            #pragma unroll
            for (int i = 0; i < 8; ++i)
                #pragma unroll
                for (int j = 0; j < 8; ++j)
                    acc[i][j] += av[i] * bv[j];
        }
        __syncthreads();
    }

    #pragma unroll
    for (int r = 0; r < 2; ++r)
        #pragma unroll
        for (int i = 0; i < 4; ++i) {
            int m = m0 + r * 64 + ty * 4 + i;
            float bb = bi ? ldin(bi, m, bf) : 0.f;
            #pragma unroll
            for (int c = 0; c < 2; ++c)
                #pragma unroll
                for (int j = 0; j < 4; ++j) {
                    long idx = (long)m * c_ms + p0 + c * 64 + tx * 4 + j;
                    float v = acc[r * 4 + i][c * 4 + j];
                    if (accum == 1) C2[sstride * ks + idx] = v;
                    else if (accum == 2) C2[idx] += v;
                    else C2[idx] = v + bb;
                }
        }
}

// ---------------- split-buffer reduction (+bias) ----------------
__global__ void reduce_k(const float* __restrict__ bufs, float* __restrict__ out,
                         int n4, int ns, long sstride, const void* __restrict__ b1,
                         const void* __restrict__ b2, int rshift, int cshift, int cmask,
                         const int* __restrict__ flagp)
{
    int bf = *flagp;
    int i = blockIdx.x * 256 + threadIdx.x;
    if (i >= n4) return;
    long e = (long)i * 4;
    float4 s = *(const float4*)(bufs + e);
    for (int k = 1; k < ns; ++k) {
        float4 v = *(const float4*)(bufs + (long)k * sstride + e);
        s.x += v.x; s.y += v.y; s.z += v.z; s.w += v.w;
    }
    const void* bp = (rshift >= 0 && ((e >> rshift) & 3) >= 2) ? b2 : b1;
    int c = (int)((e >> cshift) & cmask);
    float bb = ldin(bp, c, bf);
    *(float4*)(out + e) = make_float4(s.x + bb, s.y + bb, s.z + bb, s.w + bb);
}

// ---------------- GroupNorm (in place) + ReLU ----------------
__global__ __launch_bounds__(1024) void gn_relu_k(
    float* __restrict__ buf, const void* __restrict__ g, const void* __restrict__ bt,
    int C, int S, int groups, const int* __restrict__ flagp)
{
    int bf = *flagp;
    int nt = blockDim.x;
    int gid = blockIdx.x;
    int b = gid / groups, gr = gid % groups;
    int cpg = C / groups;
    long cnt = (long)cpg * S;
    float* base = buf + ((long)b * C + (long)gr * cpg) * S;
    double s = 0.0, s2 = 0.0;
    for (long i = threadIdx.x; i < cnt; i += nt) {
        float v = base[i];
        s += v; s2 += (double)v * v;
    }
    __shared__ double rs[1024], rq[1024];
    rs[threadIdx.x] = s; rq[threadIdx.x] = s2;
    __syncthreads();
    for (int off = nt >> 1; off > 0; off >>= 1) {
        if (threadIdx.x < off) { rs[threadIdx.x] += rs[threadIdx.x + off]; rq[threadIdx.x] += rq[threadIdx.x + off]; }
        __syncthreads();
    }
    double mean_d = rs[0] / (double)cnt;
    float mean = (float)mean_d;
    float var = (float)(rq[0] / (double)cnt - mean_d * mean_d);
    float rstd = rsqrtf(var + 1e-5f);
    for (long i = threadIdx.x; i < cnt; i += nt) {
        int c = gr * cpg + (int)(i / S);
        float v = (base[i] - mean) * rstd * ldin(g, c, bf) + ldin(bt, c, bf);
        base[i] = v > 0.f ? v : 0.f;
    }
}

// ---------------- sparse mask table (+ per-column tap count) ----------------
__global__ __launch_bounds__(384) void build_table_k(
    const void* __restrict__ mask, int* __restrict__ tabd,
    float* __restrict__ tabw, int* __restrict__ tabc,
    const int* __restrict__ flagp)
{
    int bf = *flagp;
    int nw = blockIdx.x;
    int w = nw >> 5, n = nw & 31;
    int tid = threadIdx.x;
    int d = tid - 165;
    float v = 0.f;
    if (d <= 165) {
        if (d < 0) v = ldin(mask, (long)(254 + d) * 65536 + ((long)n * 256 + 254) * 8 + w, bf);
        else       v = ldin(mask, (long)(1 + d) * 65536 + ((long)n * 256 + 1) * 8 + w, bf);
    }
    __shared__ unsigned char nz[384];
    __shared__ int scnt;
    if (tid == 0) scnt = 0;
    nz[tid] = (v != 0.f) ? 1 : 0;
    if (tid < 6) { tabd[nw * 6 + tid] = 0; tabw[nw * 6 + tid] = 0.f; }
    __syncthreads();
    if (v != 0.f) {
        atomicAdd(&scnt, 1);
        int slot = 0;
        for (int j = 0; j < tid; ++j) slot += nz[j];
        if (slot < 6) { tabd[nw * 6 + slot] = d; tabw[nw * 6 + slot] = v; }
    }
    __syncthreads();
    if (tid == 0) tabc[nw] = scnt < 6 ? scnt : 6;
}

__global__ void build_corr_k(const void* __restrict__ mask, const int* __restrict__ tabd,
                             const float* __restrict__ tabw, float* __restrict__ corrB,
                             const int* __restrict__ flagp) {
    int bf = *flagp;
    int idx = blockIdx.x * 256 + threadIdx.x;   // 65536
    if (idx >= 65536) return;
    int n = idx >> 11, p = idx & 2047;
    int t = p >> 3, w = p & 7;
    float mv = ldin(mask, ((long)n * 256 + t) * 8 + w, bf);
    float sub = 0.f;
    int base = (w * 32 + n) * 6;
    for (int k = 0; k < 6; ++k)
        if (tabd[base + k] == -t && tabw[base + k] != 0.f) sub += tabw[base + k];
    corrB[idx] = mv - sub;
}

// p0t[(b*32+n)*512 + h3] = P[b][h3][n][0]
__global__ void p0t_k(const float* __restrict__ P, float* __restrict__ p0t) {
    int idx = blockIdx.x * 256 + threadIdx.x;   // 32768
    if (idx >= 32768) return;
    int h3 = idx & 511, n = (idx >> 9) & 31, b = idx >> 14;
    p0t[idx] = P[(((long)(b * 512 + h3) * 32) + n) * 256];
}

// y[b][h3][t*8+w] = r3b[h3] + sum_{n,k} wt * P[b][h3][n][t+delta]
// Rows padded to 257 float2 w/ zero slot at [256]; u = min(tau, 256) replaces
// wrap+select. Taps beyond the column's actual count skipped via uniform branches.
__global__ __launch_bounds__(256) void apply_y_k(
    const float* __restrict__ P, const int* __restrict__ tabd,
    const float* __restrict__ tabw, const int* __restrict__ tabc,
    const void* __restrict__ r3b, float* __restrict__ y,
    const int* __restrict__ flagp)
{
    int bf = *flagp;
    int h3 = blockIdx.x;                 // 0..511
    __shared__ float2 Pl2[32 * 257];     // 64.3 KB, (b0,b1) pairs, zero slot per row
    __shared__ float4 Tp4[768];          // 12 KB packed (wt,d) pairs
    __shared__ int    Tc[256];           // 1 KB tap counts
    const float4* p04 = (const float4*)(P + (long)h3 * 8192);
    const float4* p14 = (const float4*)(P + (512L + h3) * 8192);
    for (int i = threadIdx.x; i < 2048; i += 256) {
        float4 a = p04[i], b = p14[i];
        int n = i >> 6;
        int t0 = (i & 63) * 4;
        float2* dst = Pl2 + n * 257 + t0;
        dst[0] = make_float2(a.x, b.x);
        dst[1] = make_float2(a.y, b.y);
        dst[2] = make_float2(a.z, b.z);
        dst[3] = make_float2(a.w, b.w);
    }
    if (threadIdx.x < 32) Pl2[threadIdx.x * 257 + 256] = make_float2(0.f, 0.f);
    float2* tp2 = (float2*)Tp4;
    for (int i = threadIdx.x; i < 1536; i += 256)
        tp2[i] = make_float2(tabw[i], __int_as_float(tabd[i]));
    Tc[threadIdx.x] = tabc[threadIdx.x];
    __syncthreads();

    int t = threadIdx.x;
    float a0[8], a1[8];
    #pragma unroll
    for (int w = 0; w < 8; ++w) { a0[w] = 0.f; a1[w] = 0.f; }

#define TAP(WT, DI) { int tau = t + (DI); \
    unsigned u = (unsigned)tau < 256u ? (unsigned)tau : 256u; \
    float2 pv = Pn[u]; a0[w] += (WT) * pv.x; a1[w] += (WT) * pv.y; }

    #pragma unroll 1
    for (int n = 0; n < 32; ++n) {
        const float2* Pn = Pl2 + n * 257;
        #pragma unroll
        for (int w = 0; w < 8; ++w) {
            int e = (w << 5) + n;
            int cnt = __builtin_amdgcn_readfirstlane(Tc[e]);
            int e4 = e * 3;
            float4 q0 = Tp4[e4];
            TAP(q0.x, __float_as_int(q0.y));
            if (cnt >= 2) {
                TAP(q0.z, __float_as_int(q0.w));
                if (cnt >= 3) {
                    float4 q1 = Tp4[e4 + 1];
                    TAP(q1.x, __float_as_int(q1.y));
                    if (cnt >= 4) {
                        TAP(q1.z, __float_as_int(q1.w));
                        if (cnt >= 5) {
                            float4 q2 = Tp4[e4 + 2];
                            TAP(q2.x, __float_as_int(q2.y));
                            if (cnt >= 6) TAP(q2.z, __float_as_int(q2.w));
                        }
                    }
                }
            }
        }
    }
#undef TAP

    float bias = ldin(r3b, h3, bf);
    long y0 = (long)h3 * 2048 + (long)t * 8;
    long y1 = y0 + 512L * 2048;
    *(float4*)(y + y0)     = make_float4(a0[0] + bias, a0[1] + bias, a0[2] + bias, a0[3] + bias);
    *(float4*)(y + y0 + 4) = make_float4(a0[4] + bias, a0[5] + bias, a0[6] + bias, a0[7] + bias);
    *(float4*)(y + y1)     = make_float4(a1[0] + bias, a1[1] + bias, a1[2] + bias, a1[3] + bias);
    *(float4*)(y + y1 + 4) = make_float4(a1[4] + bias, a1[5] + bias, a1[6] + bias, a1[7] + bias);
}

__global__ void head_out_k(const float* __restrict__ t1s, const float* __restrict__ t1e,
                           const void* __restrict__ s2w, const void* __restrict__ s2b,
                           const void* __restrict__ e2w, const void* __restrict__ e2b,
                           void* __restrict__ out, const int* __restrict__ flagp) {
    int bf = *flagp;
    int idx = blockIdx.x * 256 + threadIdx.x;   // 4096
    if (idx >= 4096) return;
    int b = idx >> 11, p = idx & 2047;
    const float* ts = t1s + (long)b * 262144 + p;
    const float* te = t1e + (long)b * 262144 + p;
    float as = ldin(s2b, 0, bf), ae = ldin(e2b, 0, bf);
    #pragma unroll 8
    for (int c = 0; c < 128; ++c) {
        as += ldin(s2w, c, bf) * ts[(long)c * 2048];
        ae += ldin(e2w, c, bf) * te[(long)c * 2048];
    }
    float vs = 1.f / (1.f + expf(-as));
    float ve = 1.f / (1.f + expf(-ae));
    long o0 = ((long)b * 2) * 2048 + p;
    long o1 = ((long)b * 2 + 1) * 2048 + p;
    if (bf) {
        ((bf16*)out)[o0] = __float2bfloat16(vs);
        ((bf16*)out)[o1] = __float2bfloat16(ve);
    } else {
        ((float*)out)[o0] = vs;
        ((float*)out)[o1] = ve;
    }
}

// ---------------- launch ----------------
extern "C" void kernel_launch(void* const* d_in, const int* in_sizes, int n_in,
                              void* d_out, int out_size, void* d_ws, size_t ws_size,
                              hipStream_t stream) {
    const void* x    = d_in[0];
    const void* mask = d_in[1];
    const void* c1w  = d_in[2];
    const void* c1b  = d_in[3];
    const void* gn1g = d_in[4];
    const void* gn1b = d_in[5];
    const void* w3   = d_in[6];
    const void* r3b  = d_in[7];
    const void* gn3g = d_in[8];
    const void* gn3b = d_in[9];
    const void* w2   = d_in[10];
    const void* r2b  = d_in[11];
    const void* gn2g = d_in[12];
    const void* gn2b = d_in[13];
    const void* s1w  = d_in[14];
    const void* s1b  = d_in[15];
    const void* sgng = d_in[16];
    const void* sgnb = d_in[17];
    const void* s2w  = d_in[18];
    const void* s2b  = d_in[19];
    const void* e1w  = d_in[20];
    const void* e1b  = d_in[21];
    const void* egng = d_in[22];
    const void* egnb = d_in[23];
    const void* e2w  = d_in[24];
    const void* e2b  = d_in[25];
    float* ws = (float*)d_ws;

    // layout (floats); dead-region aliasing per pipeline timeline
    int*   flagI = (int*)(ws + 0);       // 64 reserved
    float* h     = ws + 64;              // 131072
    float* c1t   = ws + 131136;          // 393216
    float* w2t   = ws + 524352;          // 65536
    float* s1t   = ws + 589888;          // 147456
    float* e1t   = ws + 737344;          // 147456 (adjacent to s1t)
    float* corrB = ws + 884800;          // 65536
    float* tabw  = ws + 950336;          // 1536
    int*   tabd  = (int*)(ws + 951872);  // 1536
    float* p0t   = ws + 953408;          // 32768
    float* t1s   = ws + 986176;          // 524288
    float* t1e   = ws + 1510464;         // 524288 (adjacent to t1s)
    float* f     = ws + 2034752;         // 524288
    float* y     = ws + 2559040;         // 2097152
    float* w3reg = ws + 4656192;         // 4194304 (bf16 buffers live here)
    float* Pb    = ws + 8850496;         // 8388608
    int*   tabc  = (int*)(ws + 17239104); // 256 ints (tail)
    bf16*  w3b   = (bf16*)w3reg;
    bf16*  hbT   = (bf16*)(w3reg + 2097152);
    float* colx  = Pb;
    float* col   = Pb;
    float* bufs_c1 = y;
    float* bufs_r2 = Pb;
    float* bufs_hd = y;

    dim3 blk(256);
    dim3 blkG(1024);

    detect_k<<<dim3(1), blk, 0, stream>>>((const unsigned short*)x, flagI);

    // weight transposes + table extraction
    transpose_w_k<<<dim3(1536), blk, 0, stream>>>(c1w, c1t, 256, 1536, flagI);
    transpose_w_k<<<dim3(256),  blk, 0, stream>>>(w2,  w2t, 128, 512, flagI);
    transpose_w_k<<<dim3(576),  blk, 0, stream>>>(s1w, s1t, 128, 1152, flagI);
    transpose_w_k<<<dim3(576),  blk, 0, stream>>>(e1w, e1t, 128, 1152, flagI);
    transpose_w3b_k<<<dim3(512), blk, 0, stream>>>(w3, w3b, flagI);
    build_table_k<<<dim3(256), dim3(384), 0, stream>>>(mask, tabd, tabw, tabc, flagI);
    build_corr_k<<<dim3(256), blk, 0, stream>>>(mask, tabd, tabw, corrB, flagI);

    // conv1: im2col + split-K(8) GEMM into buffers + reduce(+bias) + GN1 + ReLU
    im2col_x_k<<<dim3(3072), blk, 0, stream>>>(x, colx, flagI);
    gemm_t<64,64,4,4><<<dim3(4,4,16), blk, 0, stream>>>(
        c1t, colx, bufs_c1, nullptr, nullptr, 256, 1536, 256,
        1, 1, 0L, 393216L, 65536L, 0L, 256, 2, 8, 131072L, 1, flagI);
    reduce_k<<<dim3(128), blk, 0, stream>>>(bufs_c1, h, 32768, 8, 131072L,
                                            c1b, nullptr, -1, 8, 255, flagI);
    gn_relu_k<<<dim3(64), blkG, 0, stream>>>(h, gn1g, gn1b, 256, 256, 32, flagI);

    // P-GEMM via bf16 MFMA: cast h -> hbT, then pgemm_mfma
    cast_hT_k<<<dim3(512), blk, 0, stream>>>(h, hbT);
    pgemm_mfma<<<dim3(1, 8, 64), blk, 0, stream>>>(w3b, hbT, Pb);

    // sparse mask apply + bin-0 correction (plain RMW, single writer) + GN3 + ReLU
    apply_y_k<<<dim3(512), blk, 0, stream>>>(Pb, tabd, tabw, tabc, r3b, y, flagI);
    p0t_k<<<dim3(128), blk, 0, stream>>>(Pb, p0t);
    gemm_t<64,64,4,4><<<dim3(32,8,2), blk, 0, stream>>>(
        p0t, corrB, y, nullptr, nullptr, 512, 32, 2048,
        2, 1, 16384L, 0L, 0L, 1048576L, 2048, 2, 1, 0L, 2, flagI);
    gn_relu_k<<<dim3(64), blkG, 0, stream>>>(y, gn3g, gn3b, 512, 2048, 32, flagI);

    // r2d 1x1: split-K(4) GEMM into buffers + reduce(+bias) + GN2 + ReLU
    gemm_t<64,64,4,4><<<dim3(32,2,8), blk, 0, stream>>>(
        w2t, y, bufs_r2, nullptr, nullptr, 128, 512, 2048,
        1, 1, 0L, 1048576L, 262144L, 0L, 2048, 2, 4, 524288L, 1, flagI);
    reduce_k<<<dim3(512), blk, 0, stream>>>(bufs_r2, f, 131072, 4, 524288L,
                                            r2b, nullptr, -1, 11, 127, flagI);
    gn_relu_k<<<dim3(64), blkG, 0, stream>>>(f, gn2g, gn2b, 128, 2048, 32, flagI);

    // heads: shared im2col + split-K(6) quad GEMM into buffers + reduce(+bias) + GN + ReLU
    im2col_f_k<<<dim3(18432), blk, 0, stream>>>(f, col);
    gemm_q<<<dim3(16,1,24), blk, 0, stream>>>(
        s1t, col, bufs_hd, nullptr, nullptr, 128, 1152, 2048,
        2, 2, 147456L, 2359296L, 262144L, 524288L, 2048, 4, 6, 1048576L, 1, flagI);
    reduce_k<<<dim3(1024), blk, 0, stream>>>(bufs_hd, t1s, 262144, 6, 1048576L,
                                             s1b, e1b, 18, 11, 127, flagI);
    gn_relu_k<<<dim3(64), blkG, 0, stream>>>(t1s, sgng, sgnb, 128, 2048, 32, flagI);
    gn_relu_k<<<dim3(64), blkG, 0, stream>>>(t1e, egng, egnb, 128, 2048, 32, flagI);

    // 1x1 head convs + sigmoid -> output
    head_out_k<<<dim3(16), blk, 0, stream>>>(t1s, t1e, s2w, s2b, e2w, e2b, d_out, flagI);
}

// Round 13
// 456.202 us; speedup vs baseline: 1.0507x; 1.0507x over previous
//
#include <hip/hip_runtime.h>
#include <hip/hip_bf16.h>

typedef __hip_bfloat16 bf16;
typedef __attribute__((ext_vector_type(8))) short short8;
typedef __attribute__((ext_vector_type(4))) float f32x4;

static __device__ __forceinline__ float b2f(bf16 v) { return __bfloat162float(v); }

// flag-aware input load: bf==1 -> bf16, bf==0 -> f32
static __device__ __forceinline__ float ldin(const void* p, long i, int bf) {
    return bf ? b2f(((const bf16*)p)[i]) : ((const float*)p)[i];
}

// ---------------- dtype detect ----------------
__global__ void detect_k(const unsigned short* __restrict__ x16, int* __restrict__ flag) {
    __shared__ int cnt[256];
    unsigned short u = x16[threadIdx.x];
    int e = (u >> 7) & 0xFF;
    cnt[threadIdx.x] = (e >= 100 && e <= 140) ? 1 : 0;
    __syncthreads();
    for (int off = 128; off > 0; off >>= 1) {
        if (threadIdx.x < off) cnt[threadIdx.x] += cnt[threadIdx.x + off];
        __syncthreads();
    }
    if (threadIdx.x == 0) *flag = (cnt[0] > 217) ? 1 : 0;
}

// ---------------- casts / transposes ----------------
// elementwise cast to bf16 (identity when input already bf16)
__global__ void cast_bf_k(const void* __restrict__ in, bf16* __restrict__ out,
                          int n, const int* __restrict__ flagp) {
    int bf = *flagp;
    int idx = blockIdx.x * 256 + threadIdx.x;
    if (idx >= n) return;
    out[idx] = __float2bfloat16(ldin(in, idx, bf));
}

// out[k*M + m] = in[m*K + k]  (fp32, for r2d)
__global__ void transpose_w_k(const void* __restrict__ in, float* __restrict__ out,
                              int M, int K, const int* __restrict__ flagp) {
    int bf = *flagp;
    int idx = blockIdx.x * 256 + threadIdx.x;
    if (idx >= M * K) return;
    int k = idx / M, m = idx - k * M;
    out[idx] = ldin(in, (long)m * K + k, bf);
}

// w3b[n][h3][c] (bf16) from w3[(h3*256+c)*32+n]
__global__ __launch_bounds__(256) void transpose_w3b_k(const void* __restrict__ w3,
                                                       bf16* __restrict__ out,
                                                       const int* __restrict__ flagp) {
    int bf = *flagp;
    int h3 = blockIdx.x;     // 512
    __shared__ bf16 t[8192];
    long base = (long)h3 * 8192;
    for (int i = threadIdx.x; i < 8192; i += 256)
        t[i] = __float2bfloat16(ldin(w3, base + i, bf));
    __syncthreads();
    for (int i = threadIdx.x; i < 8192; i += 256) {
        int n = i >> 8, c = i & 255;
        out[((long)n * 512 + h3) * 256 + c] = t[c * 32 + n];
    }
}

// hbT[b][tau][c] (bf16) from h[b][c][tau] (fp32)
__global__ void cast_hT_k(const float* __restrict__ h, bf16* __restrict__ out) {
    int idx = blockIdx.x * 256 + threadIdx.x;   // 131072
    if (idx >= 131072) return;
    int b = idx >> 16, r = idx & 65535;
    int tau = r >> 8, c = r & 255;
    out[idx] = __float2bfloat16(h[b * 65536 + c * 256 + tau]);
}

// ---------------- bf16 im2col ----------------
// colxb[b][t][k=c*3+q] = x[b][c][t+q-1]  (bf16, zero pad)
__global__ void im2col_xb_k(const void* __restrict__ x, bf16* __restrict__ out,
                            const int* __restrict__ flagp) {
    int bf = *flagp;
    int idx = blockIdx.x * 256 + threadIdx.x;   // 786432
    if (idx >= 786432) return;
    int b = idx / 393216;
    int rem = idx - b * 393216;
    int t = rem / 1536, k = rem - t * 1536;
    int c = k / 3, q = k - c * 3;
    int tt = t + q - 1;
    float v = (tt >= 0 && tt < 256) ? ldin(x, ((long)b * 512 + c) * 256 + tt, bf) : 0.f;
    out[idx] = __float2bfloat16(v);
}

// fcolb[b][p][k=c*9+dy*3+dx] = f[b][c][(t+dy-1)*8 + (w+dx-1)]  (bf16, zero pad)
__global__ void im2col_fb_k(const float* __restrict__ f, bf16* __restrict__ out) {
    int idx = blockIdx.x * 256 + threadIdx.x;   // 4718592
    if (idx >= 4718592) return;
    int b = idx / 2359296;
    int rem = idx - b * 2359296;
    int p = rem / 1152, k = rem - p * 1152;
    int c = k / 9, q = k - c * 9;
    int dy = q / 3, dx = q - dy * 3;
    int t = p >> 3, w = p & 7;
    int tt = t + dy - 1, ww = w + dx - 1;
    float v = (tt >= 0 && tt < 256 && ww >= 0 && ww < 8)
                  ? f[((long)b * 128 + c) * 2048 + tt * 8 + ww] : 0.f;
    out[idx] = __float2bfloat16(v);
}

// ---------------- generic weight-GEMM via MFMA ----------------
// C[z][m][p] = bias(m) + sum_k A[z/a_div][m][k] * B[z&1][p][k]  (bf16 x bf16 -> fp32)
// A rows k-contiguous (weights as stored); B rows k-contiguous (im2col output).
template<int NT>
__global__ __launch_bounds__(256) void wgemm_mfma(
    const bf16* __restrict__ A, const bf16* __restrict__ B, float* __restrict__ C,
    const void* __restrict__ bias1, const void* __restrict__ bias2,
    int M, int K, int P, int a_div, long a_zs, const int* __restrict__ flagp)
{
    int bf = *flagp;
    int z = blockIdx.z;
    const bf16* A2 = A + (long)(z / a_div) * a_zs;
    const bf16* B2 = B + (long)(z & 1) * (long)P * K;
    float* C2 = C + (long)z * M * P;
    const void* bi = (z / a_div) ? bias2 : bias1;

    int tid = threadIdx.x;
    int wv = tid >> 6, lane = tid & 63;
    int q = lane >> 4, col = lane & 15;
    int m0 = blockIdx.y * 64 + wv * 16;
    int p0 = blockIdx.x * (16 * NT);

    f32x4 acc[NT];
    #pragma unroll
    for (int i = 0; i < NT; ++i) acc[i] = (f32x4){0.f, 0.f, 0.f, 0.f};

    const short8* Ab = (const short8*)(A2 + (long)(m0 + col) * K);
    int kch = K >> 5;
    for (int kc = 0; kc < kch; ++kc) {
        short8 af = Ab[kc * 4 + q];
        #pragma unroll
        for (int nt = 0; nt < NT; ++nt) {
            const short8* Bb = (const short8*)(B2 + (long)(p0 + nt * 16 + col) * K);
            short8 bfr = Bb[kc * 4 + q];
            acc[nt] = __builtin_amdgcn_mfma_f32_16x16x32_bf16(af, bfr, acc[nt], 0, 0, 0);
        }
    }

    float bv[4];
    #pragma unroll
    for (int r = 0; r < 4; ++r) bv[r] = ldin(bi, m0 + q * 4 + r, bf);
    #pragma unroll
    for (int nt = 0; nt < NT; ++nt)
        #pragma unroll
        for (int r = 0; r < 4; ++r)
            C2[(long)(m0 + q * 4 + r) * P + p0 + nt * 16 + col] = acc[nt][r] + bv[r];
}

// ---------------- MFMA P-GEMM ----------------
// P[b, h3, n, tau] = sum_c w3[h3,c,n] * h[b,c,tau]
__global__ __launch_bounds__(256) void pgemm_mfma(
    const bf16* __restrict__ w3b, const bf16* __restrict__ hbT,
    float* __restrict__ P)
{
    int z = blockIdx.z;          // b*32 + n
    int b = z >> 5, n = z & 31;
    int bm = blockIdx.y;         // 0..7 (h3 64-strip)
    int tid = threadIdx.x;
    int wv = tid >> 6, lane = tid & 63;
    int q = lane >> 4, col = lane & 15;

    f32x4 acc[16];
    #pragma unroll
    for (int i = 0; i < 16; ++i) acc[i] = (f32x4){0.f, 0.f, 0.f, 0.f};

    const short8* Abase = (const short8*)(w3b + ((long)n * 512 + bm * 64 + wv * 16 + col) * 256);
    const short8* Bbase = (const short8*)(hbT + (long)b * 65536);

    #pragma unroll
    for (int kc = 0; kc < 8; ++kc) {
        short8 af = Abase[kc * 4 + q];
        #pragma unroll
        for (int nt = 0; nt < 16; ++nt) {
            short8 bfr = Bbase[(nt * 16 + col) * 32 + kc * 4 + q];
            acc[nt] = __builtin_amdgcn_mfma_f32_16x16x32_bf16(af, bfr, acc[nt], 0, 0, 0);
        }
    }

    long dbase = (long)b * 4194304 + (long)n * 256 +
                 (long)(bm * 64 + wv * 16 + q * 4) * 8192 + col;
    #pragma unroll
    for (int nt = 0; nt < 16; ++nt)
        #pragma unroll
        for (int r = 0; r < 4; ++r)
            P[dbase + (long)r * 8192 + nt * 16] = acc[nt][r];
}

// ---------------- generic tiled GEMM (fp32, r2d + corr) ----------------
template<int BM, int BP, int TM, int TP>
__global__ __launch_bounds__(256) void gemm_t(
    const float* __restrict__ A, const float* __restrict__ B, float* __restrict__ C,
    const void* __restrict__ bias, const void* __restrict__ bias2,
    int M, int K, int P, int az_mod, int bz_div,
    long a_zs, long b_zs, long c_zs1, long c_zs2, int c_ms,
    int zmod, int ksplit, long sstride, int accum, const int* __restrict__ flagp)
{
    int bf = *flagp;
    int zraw = blockIdx.z;
    int z = zraw % zmod;
    int ks = zraw / zmod;
    int klen = K / ksplit;
    int kbeg = ks * klen;
    int kend = kbeg + klen;
    int za = z % az_mod;
    const float* A2 = A + (long)za * a_zs;
    const float* B2 = B + (long)(z / bz_div) * b_zs;
    float* C2 = C + (long)(z / bz_div) * c_zs1 + (long)za * c_zs2;
    const void* bi = (bias2 != nullptr && za != 0) ? bias2 : bias;

    __shared__ float As[16][BM];
    __shared__ float Bs[16][BP];
    int tid = threadIdx.x;
    int ty = tid >> 4, tx = tid & 15;
    int lk = tid >> 4;
    int lma = (tid & 15) * TM;
    int lpb = (tid & 15) * TP;
    int m0 = blockIdx.y * BM, p0 = blockIdx.x * BP;

    float acc[TM][TP];
    #pragma unroll
    for (int i = 0; i < TM; ++i)
        #pragma unroll
        for (int j = 0; j < TP; ++j) acc[i][j] = 0.f;

    float ra[TM], rb[TP];
    {
        const float* ap = A2 + (long)(kbeg + lk) * M + m0 + lma;
        const float* bp = B2 + (long)(kbeg + lk) * P + p0 + lpb;
        #pragma unroll
        for (int u = 0; u < TM; ++u) ra[u] = ap[u];
        #pragma unroll
        for (int u = 0; u < TP; ++u) rb[u] = bp[u];
    }

    for (int kc = kbeg; kc < kend; kc += 16) {
        #pragma unroll
        for (int u = 0; u < TM; ++u) As[lk][lma + u] = ra[u];
        #pragma unroll
        for (int u = 0; u < TP; ++u) Bs[lk][lpb + u] = rb[u];
        __syncthreads();
        if (kc + 16 < kend) {
            const float* ap = A2 + (long)(kc + 16 + lk) * M + m0 + lma;
            const float* bp = B2 + (long)(kc + 16 + lk) * P + p0 + lpb;
            #pragma unroll
            for (int u = 0; u < TM; ++u) ra[u] = ap[u];
            #pragma unroll
            for (int u = 0; u < TP; ++u) rb[u] = bp[u];
        }
        #pragma unroll
        for (int kk = 0; kk < 16; ++kk) {
            float av[TM], bv[TP];
            #pragma unroll
            for (int i = 0; i < TM; ++i) av[i] = As[kk][ty * TM + i];
            #pragma unroll
            for (int j = 0; j < TP; ++j) bv[j] = Bs[kk][tx * TP + j];
            #pragma unroll
            for (int i = 0; i < TM; ++i)
                #pragma unroll
                for (int j = 0; j < TP; ++j)
                    acc[i][j] += av[i] * bv[j];
        }
        __syncthreads();
    }

    #pragma unroll
    for (int i = 0; i < TM; ++i) {
        int m = m0 + ty * TM + i;
        float bb = bi ? ldin(bi, m, bf) : 0.f;
        #pragma unroll
        for (int j = 0; j < TP; ++j) {
            long idx = (long)m * c_ms + p0 + tx * TP + j;
            if (accum == 1) C2[sstride * ks + idx] = acc[i][j];
            else if (accum == 2) C2[idx] += acc[i][j];
            else C2[idx] = acc[i][j] + bb;
        }
    }
}

// ---------------- split-buffer reduction (+bias) ----------------
__global__ void reduce_k(const float* __restrict__ bufs, float* __restrict__ out,
                         int n4, int ns, long sstride, const void* __restrict__ b1,
                         const void* __restrict__ b2, int rshift, int cshift, int cmask,
                         const int* __restrict__ flagp)
{
    int bf = *flagp;
    int i = blockIdx.x * 256 + threadIdx.x;
    if (i >= n4) return;
    long e = (long)i * 4;
    float4 s = *(const float4*)(bufs + e);
    for (int k = 1; k < ns; ++k) {
        float4 v = *(const float4*)(bufs + (long)k * sstride + e);
        s.x += v.x; s.y += v.y; s.z += v.z; s.w += v.w;
    }
    const void* bp = (rshift >= 0 && ((e >> rshift) & 3) >= 2) ? b2 : b1;
    int c = (int)((e >> cshift) & cmask);
    float bb = ldin(bp, c, bf);
    *(float4*)(out + e) = make_float4(s.x + bb, s.y + bb, s.z + bb, s.w + bb);
}

// ---------------- GroupNorm (in place) + ReLU ----------------
__global__ __launch_bounds__(1024) void gn_relu_k(
    float* __restrict__ buf, const void* __restrict__ g, const void* __restrict__ bt,
    int C, int S, int groups, const int* __restrict__ flagp)
{
    int bf = *flagp;
    int nt = blockDim.x;
    int gid = blockIdx.x;
    int b = gid / groups, gr = gid % groups;
    int cpg = C / groups;
    long cnt = (long)cpg * S;
    float* base = buf + ((long)b * C + (long)gr * cpg) * S;
    double s = 0.0, s2 = 0.0;
    for (long i = threadIdx.x; i < cnt; i += nt) {
        float v = base[i];
        s += v; s2 += (double)v * v;
    }
    __shared__ double rs[1024], rq[1024];
    rs[threadIdx.x] = s; rq[threadIdx.x] = s2;
    __syncthreads();
    for (int off = nt >> 1; off > 0; off >>= 1) {
        if (threadIdx.x < off) { rs[threadIdx.x] += rs[threadIdx.x + off]; rq[threadIdx.x] += rq[threadIdx.x + off]; }
        __syncthreads();
    }
    double mean_d = rs[0] / (double)cnt;
    float mean = (float)mean_d;
    float var = (float)(rq[0] / (double)cnt - mean_d * mean_d);
    float rstd = rsqrtf(var + 1e-5f);
    for (long i = threadIdx.x; i < cnt; i += nt) {
        int c = gr * cpg + (int)(i / S);
        float v = (base[i] - mean) * rstd * ldin(g, c, bf) + ldin(bt, c, bf);
        base[i] = v > 0.f ? v : 0.f;
    }
}

// ---------------- sparse mask table ----------------
__global__ __launch_bounds__(384) void build_table_k(
    const void* __restrict__ mask, int* __restrict__ tabd,
    float* __restrict__ tabw, const int* __restrict__ flagp)
{
    int bf = *flagp;
    int nw = blockIdx.x;
    int w = nw >> 5, n = nw & 31;
    int tid = threadIdx.x;
    int d = tid - 165;
    float v = 0.f;
    if (d <= 165) {
        if (d < 0) v = ldin(mask, (long)(254 + d) * 65536 + ((long)n * 256 + 254) * 8 + w, bf);
        else       v = ldin(mask, (long)(1 + d) * 65536 + ((long)n * 256 + 1) * 8 + w, bf);
    }
    __shared__ unsigned char nz[384];
    nz[tid] = (v != 0.f) ? 1 : 0;
    if (tid < 6) { tabd[nw * 6 + tid] = 0; tabw[nw * 6 + tid] = 0.f; }
    __syncthreads();
    if (v != 0.f) {
        int slot = 0;
        for (int j = 0; j < tid; ++j) slot += nz[j];
        if (slot < 6) { tabd[nw * 6 + slot] = d; tabw[nw * 6 + slot] = v; }
    }
}

__global__ void build_corr_k(const void* __restrict__ mask, const int* __restrict__ tabd,
                             const float* __restrict__ tabw, float* __restrict__ corrB,
                             const int* __restrict__ flagp) {
    int bf = *flagp;
    int idx = blockIdx.x * 256 + threadIdx.x;   // 65536
    if (idx >= 65536) return;
    int n = idx >> 11, p = idx & 2047;
    int t = p >> 3, w = p & 7;
    float mv = ldin(mask, ((long)n * 256 + t) * 8 + w, bf);
    float sub = 0.f;
    int base = (w * 32 + n) * 6;
    for (int k = 0; k < 6; ++k)
        if (tabd[base + k] == -t && tabw[base + k] != 0.f) sub += tabw[base + k];
    corrB[idx] = mv - sub;
}

// p0t[(b*32+n)*512 + h3] = P[b][h3][n][0]
__global__ void p0t_k(const float* __restrict__ P, float* __restrict__ p0t) {
    int idx = blockIdx.x * 256 + threadIdx.x;   // 32768
    if (idx >= 32768) return;
    int h3 = idx & 511, n = (idx >> 9) & 31, b = idx >> 14;
    p0t[idx] = P[(((long)(b * 512 + h3) * 32) + n) * 256];
}

// y[b][h3][t*8+w] = r3b[h3] + sum_{n,k} wt * P[b][h3][n][t+delta]
// Round-11 version: both batch rows interleaved as float2, one ds_read_b64 per tap.
__global__ __launch_bounds__(256) void apply_y_k(
    const float* __restrict__ P, const int* __restrict__ tabd,
    const float* __restrict__ tabw, const void* __restrict__ r3b,
    float* __restrict__ y, const int* __restrict__ flagp)
{
    int bf = *flagp;
    int h3 = blockIdx.x;                 // 0..511
    __shared__ float2 Pl2[8192];         // 64 KB: (b0,b1) pairs, [n*256+tau]
    __shared__ float4 Tp4[768];          // 12 KB packed (wt,d) pairs
    const float4* p04 = (const float4*)(P + (long)h3 * 8192);
    const float4* p14 = (const float4*)(P + (512L + h3) * 8192);
    float4* pl4 = (float4*)Pl2;
    for (int i = threadIdx.x; i < 2048; i += 256) {
        float4 a = p04[i], b = p14[i];
        pl4[i * 2]     = make_float4(a.x, b.x, a.y, b.y);
        pl4[i * 2 + 1] = make_float4(a.z, b.z, a.w, b.w);
    }
    float2* tp2 = (float2*)Tp4;
    for (int i = threadIdx.x; i < 1536; i += 256)
        tp2[i] = make_float2(tabw[i], __int_as_float(tabd[i]));
    __syncthreads();

    int t = threadIdx.x;
    float a0[8], a1[8];
    #pragma unroll
    for (int w = 0; w < 8; ++w) { a0[w] = 0.f; a1[w] = 0.f; }

    #pragma unroll 1
    for (int n = 0; n < 32; ++n) {
        const float2* Pn = Pl2 + (n << 8);
        #pragma unroll
        for (int w = 0; w < 8; ++w) {
            int e4 = ((w << 5) + n) * 3;
            float4 q0 = Tp4[e4], q1 = Tp4[e4 + 1], q2 = Tp4[e4 + 2];
            float wts[6] = {q0.x, q0.z, q1.x, q1.z, q2.x, q2.z};
            int   dss[6] = {__float_as_int(q0.y), __float_as_int(q0.w),
                            __float_as_int(q1.y), __float_as_int(q1.w),
                            __float_as_int(q2.y), __float_as_int(q2.w)};
            #pragma unroll
            for (int k = 0; k < 6; ++k) {
                int tau = t + dss[k];
                int idx = tau & 255;
                float wt = ((unsigned)tau < 256u) ? wts[k] : 0.f;
                float2 pv = Pn[idx];
                a0[w] += wt * pv.x;
                a1[w] += wt * pv.y;
            }
        }
    }

    float bias = ldin(r3b, h3, bf);
    long y0 = (long)h3 * 2048 + (long)t * 8;
    long y1 = y0 + 512L * 2048;
    *(float4*)(y + y0)     = make_float4(a0[0] + bias, a0[1] + bias, a0[2] + bias, a0[3] + bias);
    *(float4*)(y + y0 + 4) = make_float4(a0[4] + bias, a0[5] + bias, a0[6] + bias, a0[7] + bias);
    *(float4*)(y + y1)     = make_float4(a1[0] + bias, a1[1] + bias, a1[2] + bias, a1[3] + bias);
    *(float4*)(y + y1 + 4) = make_float4(a1[4] + bias, a1[5] + bias, a1[6] + bias, a1[7] + bias);
}

__global__ void head_out_k(const float* __restrict__ t1s, const float* __restrict__ t1e,
                           const void* __restrict__ s2w, const void* __restrict__ s2b,
                           const void* __restrict__ e2w, const void* __restrict__ e2b,
                           void* __restrict__ out, const int* __restrict__ flagp) {
    int bf = *flagp;
    int idx = blockIdx.x * 256 + threadIdx.x;   // 4096
    if (idx >= 4096) return;
    int b = idx >> 11, p = idx & 2047;
    const float* ts = t1s + (long)b * 262144 + p;
    const float* te = t1e + (long)b * 262144 + p;
    float as = ldin(s2b, 0, bf), ae = ldin(e2b, 0, bf);
    #pragma unroll 8
    for (int c = 0; c < 128; ++c) {
        as += ldin(s2w, c, bf) * ts[(long)c * 2048];
        ae += ldin(e2w, c, bf) * te[(long)c * 2048];
    }
    float vs = 1.f / (1.f + expf(-as));
    float ve = 1.f / (1.f + expf(-ae));
    long o0 = ((long)b * 2) * 2048 + p;
    long o1 = ((long)b * 2 + 1) * 2048 + p;
    if (bf) {
        ((bf16*)out)[o0] = __float2bfloat16(vs);
        ((bf16*)out)[o1] = __float2bfloat16(ve);
    } else {
        ((float*)out)[o0] = vs;
        ((float*)out)[o1] = ve;
    }
}

// ---------------- launch ----------------
extern "C" void kernel_launch(void* const* d_in, const int* in_sizes, int n_in,
                              void* d_out, int out_size, void* d_ws, size_t ws_size,
                              hipStream_t stream) {
    const void* x    = d_in[0];
    const void* mask = d_in[1];
    const void* c1w  = d_in[2];
    const void* c1b  = d_in[3];
    const void* gn1g = d_in[4];
    const void* gn1b = d_in[5];
    const void* w3   = d_in[6];
    const void* r3b  = d_in[7];
    const void* gn3g = d_in[8];
    const void* gn3b = d_in[9];
    const void* w2   = d_in[10];
    const void* r2b  = d_in[11];
    const void* gn2g = d_in[12];
    const void* gn2b = d_in[13];
    const void* s1w  = d_in[14];
    const void* s1b  = d_in[15];
    const void* sgng = d_in[16];
    const void* sgnb = d_in[17];
    const void* s2w  = d_in[18];
    const void* s2b  = d_in[19];
    const void* e1w  = d_in[20];
    const void* e1b  = d_in[21];
    const void* egng = d_in[22];
    const void* egnb = d_in[23];
    const void* e2w  = d_in[24];
    const void* e2b  = d_in[25];
    float* ws = (float*)d_ws;

    // layout (floats); dead-region aliasing per pipeline timeline
    int*   flagI = (int*)(ws + 0);       // 64 reserved
    float* h     = ws + 64;              // 131072
    float* c1t   = ws + 131136;          // 393216 (holds c1wb bf16)
    float* w2t   = ws + 524352;          // 65536
    float* s1t   = ws + 589888;          // 294912 region (holds s1wb+e1wb bf16)
    float* corrB = ws + 884800;          // 65536
    float* tabw  = ws + 950336;          // 1536
    int*   tabd  = (int*)(ws + 951872);  // 1536
    float* p0t   = ws + 953408;          // 32768
    float* t1s   = ws + 986176;          // 524288
    float* t1e   = ws + 1510464;         // 524288 (adjacent to t1s)
    float* f     = ws + 2034752;         // 524288
    float* y     = ws + 2559040;         // 2097152
    float* w3reg = ws + 4656192;         // 4194304 (bf16 buffers)
    float* Pb    = ws + 8850496;         // 8388608
    bf16*  w3b   = (bf16*)w3reg;                   // 4.19M bf16
    bf16*  hbT   = (bf16*)(w3reg + 2097152);       // 131072 bf16
    bf16*  c1wb  = (bf16*)c1t;                     // 393216 bf16
    bf16*  hwb   = (bf16*)s1t;                     // s1wb (147456) + e1wb (147456) bf16
    bf16*  colxb = (bf16*)y;                       // 786432 bf16 (y dead until apply_y)
    bf16*  fcolb = (bf16*)Pb;                      // 4718592 bf16 (Pb dead by then)
    float* bufs_r2 = Pb;                           // 4 x 524288 (before fcolb)

    dim3 blk(256);
    dim3 blkG(1024);

    detect_k<<<dim3(1), blk, 0, stream>>>((const unsigned short*)x, flagI);

    // weight prep + table extraction
    cast_bf_k<<<dim3(1536), blk, 0, stream>>>(c1w, c1wb, 393216, flagI);
    cast_bf_k<<<dim3(576),  blk, 0, stream>>>(s1w, hwb, 147456, flagI);
    cast_bf_k<<<dim3(576),  blk, 0, stream>>>(e1w, hwb + 147456, 147456, flagI);
    transpose_w_k<<<dim3(256), blk, 0, stream>>>(w2, w2t, 128, 512, flagI);
    transpose_w3b_k<<<dim3(512), blk, 0, stream>>>(w3, w3b, flagI);
    build_table_k<<<dim3(256), dim3(384), 0, stream>>>(mask, tabd, tabw, flagI);
    build_corr_k<<<dim3(256), blk, 0, stream>>>(mask, tabd, tabw, corrB, flagI);

    // conv1 via MFMA: bf16 im2col + wgemm (bias fused) + GN1 + ReLU
    im2col_xb_k<<<dim3(3072), blk, 0, stream>>>(x, colxb, flagI);
    wgemm_mfma<2><<<dim3(8, 4, 2), blk, 0, stream>>>(
        c1wb, colxb, h, c1b, c1b, 256, 1536, 256, 1, 0L, flagI);
    gn_relu_k<<<dim3(64), blkG, 0, stream>>>(h, gn1g, gn1b, 256, 256, 32, flagI);

    // P-GEMM via bf16 MFMA
    cast_hT_k<<<dim3(512), blk, 0, stream>>>(h, hbT);
    pgemm_mfma<<<dim3(1, 8, 64), blk, 0, stream>>>(w3b, hbT, Pb);

    // sparse mask apply + bin-0 correction + GN3 + ReLU
    apply_y_k<<<dim3(512), blk, 0, stream>>>(Pb, tabd, tabw, r3b, y, flagI);
    p0t_k<<<dim3(128), blk, 0, stream>>>(Pb, p0t);
    gemm_t<64,64,4,4><<<dim3(32,8,2), blk, 0, stream>>>(
        p0t, corrB, y, nullptr, nullptr, 512, 32, 2048,
        2, 1, 16384L, 0L, 0L, 1048576L, 2048, 2, 1, 0L, 2, flagI);
    gn_relu_k<<<dim3(64), blkG, 0, stream>>>(y, gn3g, gn3b, 512, 2048, 32, flagI);

    // r2d 1x1 (fp32 split-K + reduce) + GN2 + ReLU
    gemm_t<64,64,4,4><<<dim3(32,2,8), blk, 0, stream>>>(
        w2t, y, bufs_r2, nullptr, nullptr, 128, 512, 2048,
        1, 1, 0L, 1048576L, 262144L, 0L, 2048, 2, 4, 524288L, 1, flagI);
    reduce_k<<<dim3(512), blk, 0, stream>>>(bufs_r2, f, 131072, 4, 524288L,
                                            r2b, nullptr, -1, 11, 127, flagI);
    gn_relu_k<<<dim3(64), blkG, 0, stream>>>(f, gn2g, gn2b, 128, 2048, 32, flagI);

    // heads via MFMA: bf16 im2col + wgemm (bias fused, z = head*2 + b) + GN + ReLU
    im2col_fb_k<<<dim3(18432), blk, 0, stream>>>(f, fcolb);
    wgemm_mfma<8><<<dim3(16, 2, 4), blk, 0, stream>>>(
        hwb, fcolb, t1s, s1b, e1b, 128, 1152, 2048, 2, 147456L, flagI);
    gn_relu_k<<<dim3(64), blkG, 0, stream>>>(t1s, sgng, sgnb, 128, 2048, 32, flagI);
    gn_relu_k<<<dim3(64), blkG, 0, stream>>>(t1e, egng, egnb, 128, 2048, 32, flagI);

    // 1x1 head convs + sigmoid -> output
    head_out_k<<<dim3(16), blk, 0, stream>>>(t1s, t1e, s2w, s2b, e2w, e2b, d_out, flagI);
}

// Round 14
// 442.360 us; speedup vs baseline: 1.0836x; 1.0313x over previous
//
#include <hip/hip_runtime.h>
#include <hip/hip_bf16.h>

typedef __hip_bfloat16 bf16;
typedef __attribute__((ext_vector_type(8))) short short8;
typedef __attribute__((ext_vector_type(4))) float f32x4;

static __device__ __forceinline__ float b2f(bf16 v) { return __bfloat162float(v); }

static __device__ __forceinline__ float ldin(const void* p, long i, int bf) {
    return bf ? b2f(((const bf16*)p)[i]) : ((const float*)p)[i];
}

// ---------------- dtype detect ----------------
__global__ void detect_k(const unsigned short* __restrict__ x16, int* __restrict__ flag) {
    __shared__ int cnt[256];
    unsigned short u = x16[threadIdx.x];
    int e = (u >> 7) & 0xFF;
    cnt[threadIdx.x] = (e >= 100 && e <= 140) ? 1 : 0;
    __syncthreads();
    for (int off = 128; off > 0; off >>= 1) {
        if (threadIdx.x < off) cnt[threadIdx.x] += cnt[threadIdx.x + off];
        __syncthreads();
    }
    if (threadIdx.x == 0) *flag = (cnt[0] > 217) ? 1 : 0;
}

// ---------------- casts / transposes ----------------
__global__ void cast_bf_k(const void* __restrict__ in, bf16* __restrict__ out,
                          int n, const int* __restrict__ flagp) {
    int bf = *flagp;
    int idx = blockIdx.x * 256 + threadIdx.x;
    if (idx >= n) return;
    out[idx] = __float2bfloat16(ldin(in, idx, bf));
}

__global__ void transpose_w_k(const void* __restrict__ in, float* __restrict__ out,
                              int M, int K, const int* __restrict__ flagp) {
    int bf = *flagp;
    int idx = blockIdx.x * 256 + threadIdx.x;
    if (idx >= M * K) return;
    int k = idx / M, m = idx - k * M;
    out[idx] = ldin(in, (long)m * K + k, bf);
}

// w3b[n][h3][c] (bf16) from w3[(h3*256+c)*32+n]
__global__ __launch_bounds__(256) void transpose_w3b_k(const void* __restrict__ w3,
                                                       bf16* __restrict__ out,
                                                       const int* __restrict__ flagp) {
    int bf = *flagp;
    int h3 = blockIdx.x;     // 512
    __shared__ bf16 t[8192];
    long base = (long)h3 * 8192;
    for (int i = threadIdx.x; i < 8192; i += 256)
        t[i] = __float2bfloat16(ldin(w3, base + i, bf));
    __syncthreads();
    for (int i = threadIdx.x; i < 8192; i += 256) {
        int n = i >> 8, c = i & 255;
        out[((long)n * 512 + h3) * 256 + c] = t[c * 32 + n];
    }
}

// hbT[b][tau][c] (bf16) from h[b][c][tau] (fp32)
__global__ void cast_hT_k(const float* __restrict__ h, bf16* __restrict__ out) {
    int idx = blockIdx.x * 256 + threadIdx.x;   // 131072
    if (idx >= 131072) return;
    int b = idx >> 16, r = idx & 65535;
    int tau = r >> 8, c = r & 255;
    out[idx] = __float2bfloat16(h[b * 65536 + c * 256 + tau]);
}

// ---------------- bf16 im2col ----------------
__global__ void im2col_xb_k(const void* __restrict__ x, bf16* __restrict__ out,
                            const int* __restrict__ flagp) {
    int bf = *flagp;
    int idx = blockIdx.x * 256 + threadIdx.x;   // 786432
    if (idx >= 786432) return;
    int b = idx / 393216;
    int rem = idx - b * 393216;
    int t = rem / 1536, k = rem - t * 1536;
    int c = k / 3, q = k - c * 3;
    int tt = t + q - 1;
    float v = (tt >= 0 && tt < 256) ? ldin(x, ((long)b * 512 + c) * 256 + tt, bf) : 0.f;
    out[idx] = __float2bfloat16(v);
}

__global__ void im2col_fb_k(const float* __restrict__ f, bf16* __restrict__ out) {
    int idx = blockIdx.x * 256 + threadIdx.x;   // 4718592
    if (idx >= 4718592) return;
    int b = idx / 2359296;
    int rem = idx - b * 2359296;
    int p = rem / 1152, k = rem - p * 1152;
    int c = k / 9, q = k - c * 9;
    int dy = q / 3, dx = q - dy * 3;
    int t = p >> 3, w = p & 7;
    int tt = t + dy - 1, ww = w + dx - 1;
    float v = (tt >= 0 && tt < 256 && ww >= 0 && ww < 8)
                  ? f[((long)b * 128 + c) * 2048 + tt * 8 + ww] : 0.f;
    out[idx] = __float2bfloat16(v);
}

// ---------------- generic weight-GEMM via MFMA ----------------
// C[z][m][p] = bias(m) + sum_k A[z/a_div][m][k] * B[z&1][p][k]
template<int NT>
__global__ __launch_bounds__(256) void wgemm_mfma(
    const bf16* __restrict__ A, const bf16* __restrict__ B, float* __restrict__ C,
    const void* __restrict__ bias1, const void* __restrict__ bias2,
    int M, int K, int P, int a_div, long a_zs, const int* __restrict__ flagp)
{
    int bf = *flagp;
    int z = blockIdx.z;
    const bf16* A2 = A + (long)(z / a_div) * a_zs;
    const bf16* B2 = B + (long)(z & 1) * (long)P * K;
    float* C2 = C + (long)z * M * P;
    const void* bi = (z / a_div) ? bias2 : bias1;

    int tid = threadIdx.x;
    int wv = tid >> 6, lane = tid & 63;
    int q = lane >> 4, col = lane & 15;
    int m0 = blockIdx.y * 64 + wv * 16;
    int p0 = blockIdx.x * (16 * NT);

    f32x4 acc[NT];
    #pragma unroll
    for (int i = 0; i < NT; ++i) acc[i] = (f32x4){0.f, 0.f, 0.f, 0.f};

    const short8* Ab = (const short8*)(A2 + (long)(m0 + col) * K);
    int kch = K >> 5;
    for (int kc = 0; kc < kch; ++kc) {
        short8 af = Ab[kc * 4 + q];
        #pragma unroll
        for (int nt = 0; nt < NT; ++nt) {
            const short8* Bb = (const short8*)(B2 + (long)(p0 + nt * 16 + col) * K);
            short8 bfr = Bb[kc * 4 + q];
            acc[nt] = __builtin_amdgcn_mfma_f32_16x16x32_bf16(af, bfr, acc[nt], 0, 0, 0);
        }
    }

    float bv[4];
    #pragma unroll
    for (int r = 0; r < 4; ++r) bv[r] = ldin(bi, m0 + q * 4 + r, bf);
    #pragma unroll
    for (int nt = 0; nt < NT; ++nt)
        #pragma unroll
        for (int r = 0; r < 4; ++r)
            C2[(long)(m0 + q * 4 + r) * P + p0 + nt * 16 + col] = acc[nt][r] + bv[r];
}

// ---------------- MFMA P-GEMM ----------------
__global__ __launch_bounds__(256) void pgemm_mfma(
    const bf16* __restrict__ w3b, const bf16* __restrict__ hbT,
    float* __restrict__ P)
{
    int z = blockIdx.z;          // b*32 + n
    int b = z >> 5, n = z & 31;
    int bm = blockIdx.y;         // 0..7
    int tid = threadIdx.x;
    int wv = tid >> 6, lane = tid & 63;
    int q = lane >> 4, col = lane & 15;

    f32x4 acc[16];
    #pragma unroll
    for (int i = 0; i < 16; ++i) acc[i] = (f32x4){0.f, 0.f, 0.f, 0.f};

    const short8* Abase = (const short8*)(w3b + ((long)n * 512 + bm * 64 + wv * 16 + col) * 256);
    const short8* Bbase = (const short8*)(hbT + (long)b * 65536);

    #pragma unroll
    for (int kc = 0; kc < 8; ++kc) {
        short8 af = Abase[kc * 4 + q];
        #pragma unroll
        for (int nt = 0; nt < 16; ++nt) {
            short8 bfr = Bbase[(nt * 16 + col) * 32 + kc * 4 + q];
            acc[nt] = __builtin_amdgcn_mfma_f32_16x16x32_bf16(af, bfr, acc[nt], 0, 0, 0);
        }
    }

    long dbase = (long)b * 4194304 + (long)n * 256 +
                 (long)(bm * 64 + wv * 16 + q * 4) * 8192 + col;
    #pragma unroll
    for (int nt = 0; nt < 16; ++nt)
        #pragma unroll
        for (int r = 0; r < 4; ++r)
            P[dbase + (long)r * 8192 + nt * 16] = acc[nt][r];
}

// ---------------- generic tiled GEMM (fp32, r2d + corr) ----------------
template<int BM, int BP, int TM, int TP>
__global__ __launch_bounds__(256) void gemm_t(
    const float* __restrict__ A, const float* __restrict__ B, float* __restrict__ C,
    const void* __restrict__ bias, const void* __restrict__ bias2,
    int M, int K, int P, int az_mod, int bz_div,
    long a_zs, long b_zs, long c_zs1, long c_zs2, int c_ms,
    int zmod, int ksplit, long sstride, int accum, const int* __restrict__ flagp)
{
    int bf = *flagp;
    int zraw = blockIdx.z;
    int z = zraw % zmod;
    int ks = zraw / zmod;
    int klen = K / ksplit;
    int kbeg = ks * klen;
    int kend = kbeg + klen;
    int za = z % az_mod;
    const float* A2 = A + (long)za * a_zs;
    const float* B2 = B + (long)(z / bz_div) * b_zs;
    float* C2 = C + (long)(z / bz_div) * c_zs1 + (long)za * c_zs2;
    const void* bi = (bias2 != nullptr && za != 0) ? bias2 : bias;

    __shared__ float As[16][BM];
    __shared__ float Bs[16][BP];
    int tid = threadIdx.x;
    int ty = tid >> 4, tx = tid & 15;
    int lk = tid >> 4;
    int lma = (tid & 15) * TM;
    int lpb = (tid & 15) * TP;
    int m0 = blockIdx.y * BM, p0 = blockIdx.x * BP;

    float acc[TM][TP];
    #pragma unroll
    for (int i = 0; i < TM; ++i)
        #pragma unroll
        for (int j = 0; j < TP; ++j) acc[i][j] = 0.f;

    float ra[TM], rb[TP];
    {
        const float* ap = A2 + (long)(kbeg + lk) * M + m0 + lma;
        const float* bp = B2 + (long)(kbeg + lk) * P + p0 + lpb;
        #pragma unroll
        for (int u = 0; u < TM; ++u) ra[u] = ap[u];
        #pragma unroll
        for (int u = 0; u < TP; ++u) rb[u] = bp[u];
    }

    for (int kc = kbeg; kc < kend; kc += 16) {
        #pragma unroll
        for (int u = 0; u < TM; ++u) As[lk][lma + u] = ra[u];
        #pragma unroll
        for (int u = 0; u < TP; ++u) Bs[lk][lpb + u] = rb[u];
        __syncthreads();
        if (kc + 16 < kend) {
            const float* ap = A2 + (long)(kc + 16 + lk) * M + m0 + lma;
            const float* bp = B2 + (long)(kc + 16 + lk) * P + p0 + lpb;
            #pragma unroll
            for (int u = 0; u < TM; ++u) ra[u] = ap[u];
            #pragma unroll
            for (int u = 0; u < TP; ++u) rb[u] = bp[u];
        }
        #pragma unroll
        for (int kk = 0; kk < 16; ++kk) {
            float av[TM], bv[TP];
            #pragma unroll
            for (int i = 0; i < TM; ++i) av[i] = As[kk][ty * TM + i];
            #pragma unroll
            for (int j = 0; j < TP; ++j) bv[j] = Bs[kk][tx * TP + j];
            #pragma unroll
            for (int i = 0; i < TM; ++i)
                #pragma unroll
                for (int j = 0; j < TP; ++j)
                    acc[i][j] += av[i] * bv[j];
        }
        __syncthreads();
    }

    #pragma unroll
    for (int i = 0; i < TM; ++i) {
        int m = m0 + ty * TM + i;
        float bb = bi ? ldin(bi, m, bf) : 0.f;
        #pragma unroll
        for (int j = 0; j < TP; ++j) {
            long idx = (long)m * c_ms + p0 + tx * TP + j;
            if (accum == 1) C2[sstride * ks + idx] = acc[i][j];
            else if (accum == 2) C2[idx] += acc[i][j];
            else C2[idx] = acc[i][j] + bb;
        }
    }
}

// ---------------- split-buffer reduction (+bias) ----------------
__global__ void reduce_k(const float* __restrict__ bufs, float* __restrict__ out,
                         int n4, int ns, long sstride, const void* __restrict__ b1,
                         const void* __restrict__ b2, int rshift, int cshift, int cmask,
                         const int* __restrict__ flagp)
{
    int bf = *flagp;
    int i = blockIdx.x * 256 + threadIdx.x;
    if (i >= n4) return;
    long e = (long)i * 4;
    float4 s = *(const float4*)(bufs + e);
    for (int k = 1; k < ns; ++k) {
        float4 v = *(const float4*)(bufs + (long)k * sstride + e);
        s.x += v.x; s.y += v.y; s.z += v.z; s.w += v.w;
    }
    const void* bp = (rshift >= 0 && ((e >> rshift) & 3) >= 2) ? b2 : b1;
    int c = (int)((e >> cshift) & cmask);
    float bb = ldin(bp, c, bf);
    *(float4*)(out + e) = make_float4(s.x + bb, s.y + bb, s.z + bb, s.w + bb);
}

// ---------------- GroupNorm: single-kernel (small) ----------------
__global__ __launch_bounds__(1024) void gn_relu_k(
    float* __restrict__ buf, const void* __restrict__ g, const void* __restrict__ bt,
    int C, int S, int groups, const int* __restrict__ flagp)
{
    int bf = *flagp;
    int nt = blockDim.x;
    int gid = blockIdx.x;
    int b = gid / groups, gr = gid % groups;
    int cpg = C / groups;
    long cnt = (long)cpg * S;
    float* base = buf + ((long)b * C + (long)gr * cpg) * S;
    double s = 0.0, s2 = 0.0;
    for (long i = threadIdx.x; i < cnt; i += nt) {
        float v = base[i];
        s += v; s2 += (double)v * v;
    }
    __shared__ double rs[1024], rq[1024];
    rs[threadIdx.x] = s; rq[threadIdx.x] = s2;
    __syncthreads();
    for (int off = nt >> 1; off > 0; off >>= 1) {
        if (threadIdx.x < off) { rs[threadIdx.x] += rs[threadIdx.x + off]; rq[threadIdx.x] += rq[threadIdx.x + off]; }
        __syncthreads();
    }
    double mean_d = rs[0] / (double)cnt;
    float mean = (float)mean_d;
    float var = (float)(rq[0] / (double)cnt - mean_d * mean_d);
    float rstd = rsqrtf(var + 1e-5f);
    for (long i = threadIdx.x; i < cnt; i += nt) {
        int c = gr * cpg + (int)(i / S);
        float v = (base[i] - mean) * rstd * ldin(g, c, bf) + ldin(bt, c, bf);
        base[i] = v > 0.f ? v : 0.f;
    }
}

// ---------------- GroupNorm: two-phase (large) ----------------
// phase 1: per-(group,chunk) partial sums -> part[blk*2..+1]
__global__ __launch_bounds__(256) void gn_part_k(
    const float* __restrict__ buf, double* __restrict__ part,
    int C, int S, int groups, int chunks)
{
    int gi = blockIdx.x / chunks, ch = blockIdx.x % chunks;
    int b = gi / groups, gr = gi % groups;
    int cpg = C / groups;
    long cnt = (long)cpg * S;
    long clen = cnt / chunks;
    const float* base = buf + ((long)b * C + (long)gr * cpg) * S + (long)ch * clen;
    double s = 0.0, s2 = 0.0;
    for (long i = threadIdx.x; i < clen; i += 256) {
        float v = base[i];
        s += v; s2 += (double)v * v;
    }
    __shared__ double rs[256], rq[256];
    rs[threadIdx.x] = s; rq[threadIdx.x] = s2;
    __syncthreads();
    for (int off = 128; off > 0; off >>= 1) {
        if (threadIdx.x < off) { rs[threadIdx.x] += rs[threadIdx.x + off]; rq[threadIdx.x] += rq[threadIdx.x + off]; }
        __syncthreads();
    }
    if (threadIdx.x == 0) { part[blockIdx.x * 2] = rs[0]; part[blockIdx.x * 2 + 1] = rq[0]; }
}

// phase 2: finalize stats (deterministic order) + normalize + ReLU
__global__ __launch_bounds__(256) void gn_apply_k(
    float* __restrict__ buf, const double* __restrict__ part,
    const void* __restrict__ g, const void* __restrict__ bt,
    int C, int S, int groups, int chunks, const int* __restrict__ flagp)
{
    int bf = *flagp;
    int gi = blockIdx.x / chunks, ch = blockIdx.x % chunks;
    int b = gi / groups, gr = gi % groups;
    int cpg = C / groups;
    long cnt = (long)cpg * S;
    long clen = cnt / chunks;
    double s = 0.0, s2 = 0.0;
    for (int k = 0; k < chunks; ++k) {
        s += part[(gi * chunks + k) * 2];
        s2 += part[(gi * chunks + k) * 2 + 1];
    }
    double mean_d = s / (double)cnt;
    float mean = (float)mean_d;
    float var = (float)(s2 / (double)cnt - mean_d * mean_d);
    float rstd = rsqrtf(var + 1e-5f);
    float* base = buf + ((long)b * C + (long)gr * cpg) * S + (long)ch * clen;
    long off0 = (long)ch * clen;
    for (long i = threadIdx.x; i < clen; i += 256) {
        int c = gr * cpg + (int)((off0 + i) / S);
        float v = (base[i] - mean) * rstd * ldin(g, c, bf) + ldin(bt, c, bf);
        base[i] = v > 0.f ? v : 0.f;
    }
}

// ---------------- sparse mask table ----------------
__global__ __launch_bounds__(384) void build_table_k(
    const void* __restrict__ mask, int* __restrict__ tabd,
    float* __restrict__ tabw, const int* __restrict__ flagp)
{
    int bf = *flagp;
    int nw = blockIdx.x;
    int w = nw >> 5, n = nw & 31;
    int tid = threadIdx.x;
    int d = tid - 165;
    float v = 0.f;
    if (d <= 165) {
        if (d < 0) v = ldin(mask, (long)(254 + d) * 65536 + ((long)n * 256 + 254) * 8 + w, bf);
        else       v = ldin(mask, (long)(1 + d) * 65536 + ((long)n * 256 + 1) * 8 + w, bf);
    }
    __shared__ unsigned char nz[384];
    nz[tid] = (v != 0.f) ? 1 : 0;
    if (tid < 6) { tabd[nw * 6 + tid] = 0; tabw[nw * 6 + tid] = 0.f; }
    __syncthreads();
    if (v != 0.f) {
        int slot = 0;
        for (int j = 0; j < tid; ++j) slot += nz[j];
        if (slot < 6) { tabd[nw * 6 + slot] = d; tabw[nw * 6 + slot] = v; }
    }
}

__global__ void build_corr_k(const void* __restrict__ mask, const int* __restrict__ tabd,
                             const float* __restrict__ tabw, float* __restrict__ corrB,
                             const int* __restrict__ flagp) {
    int bf = *flagp;
    int idx = blockIdx.x * 256 + threadIdx.x;   // 65536
    if (idx >= 65536) return;
    int n = idx >> 11, p = idx & 2047;
    int t = p >> 3, w = p & 7;
    float mv = ldin(mask, ((long)n * 256 + t) * 8 + w, bf);
    float sub = 0.f;
    int base = (w * 32 + n) * 6;
    for (int k = 0; k < 6; ++k)
        if (tabd[base + k] == -t && tabw[base + k] != 0.f) sub += tabw[base + k];
    corrB[idx] = mv - sub;
}

// p0t[(b*32+n)*512 + h3] = P[b][h3][n][0]
__global__ void p0t_k(const float* __restrict__ P, float* __restrict__ p0t) {
    int idx = blockIdx.x * 256 + threadIdx.x;   // 32768
    if (idx >= 32768) return;
    int h3 = idx & 511, n = (idx >> 9) & 31, b = idx >> 14;
    p0t[idx] = P[(((long)(b * 512 + h3) * 32) + n) * 256];
}

// partial apply: block = (h3, half); 16 n-values staged; writes part[half] (no bias)
__global__ __launch_bounds__(256) void apply_y_k(
    const float* __restrict__ P, const int* __restrict__ tabd,
    const float* __restrict__ tabw, float* __restrict__ part,
    const int* __restrict__ flagp)
{
    int bx = blockIdx.x;                 // 0..1023
    int h3 = bx >> 1, half = bx & 1;
    int n0 = half * 16;
    __shared__ float2 Pl2[16 * 256];     // 32 KB
    __shared__ float4 Tp4[384];          // 6 KB (128 local cols x 3)
    const float4* p04 = (const float4*)(P + ((long)h3 * 32 + n0) * 256);
    const float4* p14 = (const float4*)(P + ((long)(512 + h3) * 32 + n0) * 256);
    float4* pl4 = (float4*)Pl2;
    for (int i = threadIdx.x; i < 1024; i += 256) {
        float4 a = p04[i], b = p14[i];
        pl4[i * 2]     = make_float4(a.x, b.x, a.y, b.y);
        pl4[i * 2 + 1] = make_float4(a.z, b.z, a.w, b.w);
    }
    float2* tp2 = (float2*)Tp4;
    for (int i = threadIdx.x; i < 768; i += 256) {
        int el = i / 6, k = i - el * 6;
        int ge = ((el >> 4) << 5) + n0 + (el & 15);
        tp2[i] = make_float2(tabw[ge * 6 + k], __int_as_float(tabd[ge * 6 + k]));
    }
    __syncthreads();

    int t = threadIdx.x;
    float a0[8], a1[8];
    #pragma unroll
    for (int w = 0; w < 8; ++w) { a0[w] = 0.f; a1[w] = 0.f; }

    #pragma unroll 1
    for (int nl = 0; nl < 16; ++nl) {
        const float2* Pn = Pl2 + (nl << 8);
        #pragma unroll
        for (int w = 0; w < 8; ++w) {
            int e4 = ((w << 4) + nl) * 3;
            float4 q0 = Tp4[e4], q1 = Tp4[e4 + 1], q2 = Tp4[e4 + 2];
            float wts[6] = {q0.x, q0.z, q1.x, q1.z, q2.x, q2.z};
            int   dss[6] = {__float_as_int(q0.y), __float_as_int(q0.w),
                            __float_as_int(q1.y), __float_as_int(q1.w),
                            __float_as_int(q2.y), __float_as_int(q2.w)};
            #pragma unroll
            for (int k = 0; k < 6; ++k) {
                int tau = t + dss[k];
                int idx = tau & 255;
                float wt = ((unsigned)tau < 256u) ? wts[k] : 0.f;
                float2 pv = Pn[idx];
                a0[w] += wt * pv.x;
                a1[w] += wt * pv.y;
            }
        }
    }

    long y0 = (long)half * 2097152 + (long)h3 * 2048 + (long)t * 8;
    long y1 = y0 + 512L * 2048;
    *(float4*)(part + y0)     = make_float4(a0[0], a0[1], a0[2], a0[3]);
    *(float4*)(part + y0 + 4) = make_float4(a0[4], a0[5], a0[6], a0[7]);
    *(float4*)(part + y1)     = make_float4(a1[0], a1[1], a1[2], a1[3]);
    *(float4*)(part + y1 + 4) = make_float4(a1[4], a1[5], a1[6], a1[7]);
}

// y = part[half0] + part[half1] + r3b[h3]
__global__ void merge_y_k(const float* __restrict__ part, float* __restrict__ y,
                          const void* __restrict__ r3b, const int* __restrict__ flagp) {
    int bf = *flagp;
    int i = blockIdx.x * 256 + threadIdx.x;   // 524288 float4
    if (i >= 524288) return;
    const float4* p4 = (const float4*)part;
    float4 a = p4[i], b = p4[i + 524288];
    long e = (long)i * 4;
    int h3 = (int)((e >> 11) & 511);
    float bb = ldin(r3b, h3, bf);
    ((float4*)y)[i] = make_float4(a.x + b.x + bb, a.y + b.y + bb,
                                  a.z + b.z + bb, a.w + b.w + bb);
}

__global__ __launch_bounds__(64) void head_out_k(
    const float* __restrict__ t1s, const float* __restrict__ t1e,
    const void* __restrict__ s2w, const void* __restrict__ s2b,
    const void* __restrict__ e2w, const void* __restrict__ e2b,
    void* __restrict__ out, const int* __restrict__ flagp) {
    int bf = *flagp;
    int idx = blockIdx.x * 64 + threadIdx.x;   // 4096
    if (idx >= 4096) return;
    int b = idx >> 11, p = idx & 2047;
    const float* ts = t1s + (long)b * 262144 + p;
    const float* te = t1e + (long)b * 262144 + p;
    float as = ldin(s2b, 0, bf), ae = ldin(e2b, 0, bf);
    #pragma unroll 8
    for (int c = 0; c < 128; ++c) {
        as += ldin(s2w, c, bf) * ts[(long)c * 2048];
        ae += ldin(e2w, c, bf) * te[(long)c * 2048];
    }
    float vs = 1.f / (1.f + expf(-as));
    float ve = 1.f / (1.f + expf(-ae));
    long o0 = ((long)b * 2) * 2048 + p;
    long o1 = ((long)b * 2 + 1) * 2048 + p;
    if (bf) {
        ((bf16*)out)[o0] = __float2bfloat16(vs);
        ((bf16*)out)[o1] = __float2bfloat16(ve);
    } else {
        ((float*)out)[o0] = vs;
        ((float*)out)[o1] = ve;
    }
}

// ---------------- launch ----------------
extern "C" void kernel_launch(void* const* d_in, const int* in_sizes, int n_in,
                              void* d_out, int out_size, void* d_ws, size_t ws_size,
                              hipStream_t stream) {
    const void* x    = d_in[0];
    const void* mask = d_in[1];
    const void* c1w  = d_in[2];
    const void* c1b  = d_in[3];
    const void* gn1g = d_in[4];
    const void* gn1b = d_in[5];
    const void* w3   = d_in[6];
    const void* r3b  = d_in[7];
    const void* gn3g = d_in[8];
    const void* gn3b = d_in[9];
    const void* w2   = d_in[10];
    const void* r2b  = d_in[11];
    const void* gn2g = d_in[12];
    const void* gn2b = d_in[13];
    const void* s1w  = d_in[14];
    const void* s1b  = d_in[15];
    const void* sgng = d_in[16];
    const void* sgnb = d_in[17];
    const void* s2w  = d_in[18];
    const void* s2b  = d_in[19];
    const void* e1w  = d_in[20];
    const void* e1b  = d_in[21];
    const void* egng = d_in[22];
    const void* egnb = d_in[23];
    const void* e2w  = d_in[24];
    const void* e2b  = d_in[25];
    float* ws = (float*)d_ws;

    int*   flagI = (int*)(ws + 0);       // 64 reserved
    float* h     = ws + 64;              // 131072
    float* c1t   = ws + 131136;          // 393216 (c1wb bf16)
    float* w2t   = ws + 524352;          // 65536
    float* s1t   = ws + 589888;          // 294912 (s1wb+e1wb bf16)
    float* corrB = ws + 884800;          // 65536
    float* tabw  = ws + 950336;          // 1536
    int*   tabd  = (int*)(ws + 951872);  // 1536
    float* p0t   = ws + 953408;          // 32768
    float* t1s   = ws + 986176;          // 524288
    float* t1e   = ws + 1510464;         // 524288
    float* f     = ws + 2034752;         // 524288
    float* y     = ws + 2559040;         // 2097152
    float* w3reg = ws + 4656192;         // 4194304 (bf16 bufs / apply partials)
    float* Pb    = ws + 8850496;         // 8388608
    double* gnbuf = (double*)(ws + 17239104); // 1024 doubles (8 KB)
    bf16*  w3b   = (bf16*)w3reg;
    bf16*  hbT   = (bf16*)(w3reg + 2097152);
    bf16*  c1wb  = (bf16*)c1t;
    bf16*  hwb   = (bf16*)s1t;
    bf16*  colxb = (bf16*)y;                       // y dead until merge
    bf16*  fcolb = (bf16*)Pb;
    float* bufs_r2 = Pb;
    float* ypart = w3reg;                          // 4M floats (w3b/hbT dead post-pgemm)

    dim3 blk(256);
    dim3 blkG(1024);

    detect_k<<<dim3(1), blk, 0, stream>>>((const unsigned short*)x, flagI);

    // weight prep + table extraction
    cast_bf_k<<<dim3(1536), blk, 0, stream>>>(c1w, c1wb, 393216, flagI);
    cast_bf_k<<<dim3(576),  blk, 0, stream>>>(s1w, hwb, 147456, flagI);
    cast_bf_k<<<dim3(576),  blk, 0, stream>>>(e1w, hwb + 147456, 147456, flagI);
    transpose_w_k<<<dim3(256), blk, 0, stream>>>(w2, w2t, 128, 512, flagI);
    transpose_w3b_k<<<dim3(512), blk, 0, stream>>>(w3, w3b, flagI);
    build_table_k<<<dim3(256), dim3(384), 0, stream>>>(mask, tabd, tabw, flagI);
    build_corr_k<<<dim3(256), blk, 0, stream>>>(mask, tabd, tabw, corrB, flagI);

    // conv1 via MFMA (NT=1, 128 blocks) + GN1 + ReLU
    im2col_xb_k<<<dim3(3072), blk, 0, stream>>>(x, colxb, flagI);
    wgemm_mfma<1><<<dim3(16, 4, 2), blk, 0, stream>>>(
        c1wb, colxb, h, c1b, c1b, 256, 1536, 256, 1, 0L, flagI);
    gn_relu_k<<<dim3(64), blkG, 0, stream>>>(h, gn1g, gn1b, 256, 256, 32, flagI);

    // P-GEMM via bf16 MFMA
    cast_hT_k<<<dim3(512), blk, 0, stream>>>(h, hbT);
    pgemm_mfma<<<dim3(1, 8, 64), blk, 0, stream>>>(w3b, hbT, Pb);

    // sparse mask apply (n-split, 1024 blocks) + merge(+bias) + corr + GN3 (2-phase)
    apply_y_k<<<dim3(1024), blk, 0, stream>>>(Pb, tabd, tabw, ypart, flagI);
    merge_y_k<<<dim3(2048), blk, 0, stream>>>(ypart, y, r3b, flagI);
    p0t_k<<<dim3(128), blk, 0, stream>>>(Pb, p0t);
    gemm_t<64,64,4,4><<<dim3(32,8,2), blk, 0, stream>>>(
        p0t, corrB, y, nullptr, nullptr, 512, 32, 2048,
        2, 1, 16384L, 0L, 0L, 1048576L, 2048, 2, 1, 0L, 2, flagI);
    gn_part_k<<<dim3(512), blk, 0, stream>>>(y, gnbuf, 512, 2048, 32, 8);
    gn_apply_k<<<dim3(512), blk, 0, stream>>>(y, gnbuf, gn3g, gn3b, 512, 2048, 32, 8, flagI);

    // r2d 1x1 (fp32 split-K + reduce) + GN2 (2-phase)
    gemm_t<64,64,4,4><<<dim3(32,2,8), blk, 0, stream>>>(
        w2t, y, bufs_r2, nullptr, nullptr, 128, 512, 2048,
        1, 1, 0L, 1048576L, 262144L, 0L, 2048, 2, 4, 524288L, 1, flagI);
    reduce_k<<<dim3(512), blk, 0, stream>>>(bufs_r2, f, 131072, 4, 524288L,
                                            r2b, nullptr, -1, 11, 127, flagI);
    gn_part_k<<<dim3(256), blk, 0, stream>>>(f, gnbuf, 128, 2048, 32, 4);
    gn_apply_k<<<dim3(256), blk, 0, stream>>>(f, gnbuf, gn2g, gn2b, 128, 2048, 32, 4, flagI);

    // heads via MFMA (NT=4, 256 blocks) + GN (2-phase each)
    im2col_fb_k<<<dim3(18432), blk, 0, stream>>>(f, fcolb);
    wgemm_mfma<4><<<dim3(32, 2, 4), blk, 0, stream>>>(
        hwb, fcolb, t1s, s1b, e1b, 128, 1152, 2048, 2, 147456L, flagI);
    gn_part_k<<<dim3(256), blk, 0, stream>>>(t1s, gnbuf, 128, 2048, 32, 4);
    gn_apply_k<<<dim3(256), blk, 0, stream>>>(t1s, gnbuf, sgng, sgnb, 128, 2048, 32, 4, flagI);
    gn_part_k<<<dim3(256), blk, 0, stream>>>(t1e, gnbuf, 128, 2048, 32, 4);
    gn_apply_k<<<dim3(256), blk, 0, stream>>>(t1e, gnbuf, egng, egnb, 128, 2048, 32, 4, flagI);

    // 1x1 head convs + sigmoid -> output
    head_out_k<<<dim3(64), dim3(64), 0, stream>>>(t1s, t1e, s2w, s2b, e2w, e2b, d_out, flagI);
}

// Round 15
// 432.592 us; speedup vs baseline: 1.1081x; 1.0226x over previous
//
#include <hip/hip_runtime.h>
#include <hip/hip_bf16.h>

typedef __hip_bfloat16 bf16;
typedef __attribute__((ext_vector_type(8))) short short8;
typedef __attribute__((ext_vector_type(4))) float f32x4;

static __device__ __forceinline__ float b2f(bf16 v) { return __bfloat162float(v); }

static __device__ __forceinline__ float ldin(const void* p, long i, int bf) {
    return bf ? b2f(((const bf16*)p)[i]) : ((const float*)p)[i];
}

// ---------------- dtype detect ----------------
__global__ void detect_k(const unsigned short* __restrict__ x16, int* __restrict__ flag) {
    __shared__ int cnt[256];
    unsigned short u = x16[threadIdx.x];
    int e = (u >> 7) & 0xFF;
    cnt[threadIdx.x] = (e >= 100 && e <= 140) ? 1 : 0;
    __syncthreads();
    for (int off = 128; off > 0; off >>= 1) {
        if (threadIdx.x < off) cnt[threadIdx.x] += cnt[threadIdx.x + off];
        __syncthreads();
    }
    if (threadIdx.x == 0) *flag = (cnt[0] > 217) ? 1 : 0;
}

// ---------------- casts / transposes ----------------
__global__ void cast_bf_k(const void* __restrict__ in, bf16* __restrict__ out,
                          int n, const int* __restrict__ flagp) {
    int bf = *flagp;
    int idx = blockIdx.x * 256 + threadIdx.x;
    if (idx >= n) return;
    out[idx] = __float2bfloat16(ldin(in, idx, bf));
}

// w3b[n][h3][c] (bf16) from w3[(h3*256+c)*32+n]
__global__ __launch_bounds__(256) void transpose_w3b_k(const void* __restrict__ w3,
                                                       bf16* __restrict__ out,
                                                       const int* __restrict__ flagp) {
    int bf = *flagp;
    int h3 = blockIdx.x;     // 512
    __shared__ bf16 t[8192];
    long base = (long)h3 * 8192;
    for (int i = threadIdx.x; i < 8192; i += 256)
        t[i] = __float2bfloat16(ldin(w3, base + i, bf));
    __syncthreads();
    for (int i = threadIdx.x; i < 8192; i += 256) {
        int n = i >> 8, c = i & 255;
        out[((long)n * 512 + h3) * 256 + c] = t[c * 32 + n];
    }
}

// hbT[b][tau][c] (bf16) from h[b][c][tau] (fp32)
__global__ void cast_hT_k(const float* __restrict__ h, bf16* __restrict__ out) {
    int idx = blockIdx.x * 256 + threadIdx.x;   // 131072
    if (idx >= 131072) return;
    int b = idx >> 16, r = idx & 65535;
    int tau = r >> 8, c = r & 255;
    out[idx] = __float2bfloat16(h[b * 65536 + c * 256 + tau]);
}

// yT[b][p][c] (bf16) from y[b][c=512][p=2048] (fp32), 64x64 LDS tile
__global__ __launch_bounds__(256) void castT_k(const float* __restrict__ y,
                                               bf16* __restrict__ yT) {
    int p0 = blockIdx.x * 64, c0 = blockIdx.y * 64, b = blockIdx.z;
    __shared__ bf16 t[64][65];
    const float* src = y + (long)b * 1048576;
    for (int i = threadIdx.x; i < 4096; i += 256) {
        int cl = i >> 6, pl = i & 63;
        t[pl][cl] = __float2bfloat16(src[(long)(c0 + cl) * 2048 + p0 + pl]);
    }
    __syncthreads();
    bf16* dst = yT + (long)b * 1048576;
    for (int i = threadIdx.x; i < 4096; i += 256) {
        int pl = i >> 6, cl = i & 63;
        dst[(long)(p0 + pl) * 512 + c0 + cl] = t[pl][cl];
    }
}

// ---------------- bf16 im2col ----------------
__global__ void im2col_xb_k(const void* __restrict__ x, bf16* __restrict__ out,
                            const int* __restrict__ flagp) {
    int bf = *flagp;
    int idx = blockIdx.x * 256 + threadIdx.x;   // 786432
    if (idx >= 786432) return;
    int b = idx / 393216;
    int rem = idx - b * 393216;
    int t = rem / 1536, k = rem - t * 1536;
    int c = k / 3, q = k - c * 3;
    int tt = t + q - 1;
    float v = (tt >= 0 && tt < 256) ? ldin(x, ((long)b * 512 + c) * 256 + tt, bf) : 0.f;
    out[idx] = __float2bfloat16(v);
}

__global__ void im2col_fb_k(const float* __restrict__ f, bf16* __restrict__ out) {
    int idx = blockIdx.x * 256 + threadIdx.x;   // 4718592
    if (idx >= 4718592) return;
    int b = idx / 2359296;
    int rem = idx - b * 2359296;
    int p = rem / 1152, k = rem - p * 1152;
    int c = k / 9, q = k - c * 9;
    int dy = q / 3, dx = q - dy * 3;
    int t = p >> 3, w = p & 7;
    int tt = t + dy - 1, ww = w + dx - 1;
    float v = (tt >= 0 && tt < 256 && ww >= 0 && ww < 8)
                  ? f[((long)b * 128 + c) * 2048 + tt * 8 + ww] : 0.f;
    out[idx] = __float2bfloat16(v);
}

// ---------------- generic weight-GEMM via MFMA ----------------
// C[z][m][p] = bias(m) + sum_k A[z/a_div][m][k] * B[z&1][p][k]
template<int NT>
__global__ __launch_bounds__(256) void wgemm_mfma(
    const bf16* __restrict__ A, const bf16* __restrict__ B, float* __restrict__ C,
    const void* __restrict__ bias1, const void* __restrict__ bias2,
    int M, int K, int P, int a_div, long a_zs, const int* __restrict__ flagp)
{
    int bf = *flagp;
    int z = blockIdx.z;
    const bf16* A2 = A + (long)(z / a_div) * a_zs;
    const bf16* B2 = B + (long)(z & 1) * (long)P * K;
    float* C2 = C + (long)z * M * P;
    const void* bi = (z / a_div) ? bias2 : bias1;

    int tid = threadIdx.x;
    int wv = tid >> 6, lane = tid & 63;
    int q = lane >> 4, col = lane & 15;
    int m0 = blockIdx.y * 64 + wv * 16;
    int p0 = blockIdx.x * (16 * NT);

    f32x4 acc[NT];
    #pragma unroll
    for (int i = 0; i < NT; ++i) acc[i] = (f32x4){0.f, 0.f, 0.f, 0.f};

    const short8* Ab = (const short8*)(A2 + (long)(m0 + col) * K);
    int kch = K >> 5;
    for (int kc = 0; kc < kch; ++kc) {
        short8 af = Ab[kc * 4 + q];
        #pragma unroll
        for (int nt = 0; nt < NT; ++nt) {
            const short8* Bb = (const short8*)(B2 + (long)(p0 + nt * 16 + col) * K);
            short8 bfr = Bb[kc * 4 + q];
            acc[nt] = __builtin_amdgcn_mfma_f32_16x16x32_bf16(af, bfr, acc[nt], 0, 0, 0);
        }
    }

    float bv[4];
    #pragma unroll
    for (int r = 0; r < 4; ++r) bv[r] = ldin(bi, m0 + q * 4 + r, bf);
    #pragma unroll
    for (int nt = 0; nt < NT; ++nt)
        #pragma unroll
        for (int r = 0; r < 4; ++r)
            C2[(long)(m0 + q * 4 + r) * P + p0 + nt * 16 + col] = acc[nt][r] + bv[r];
}

// ---------------- MFMA P-GEMM ----------------
__global__ __launch_bounds__(256) void pgemm_mfma(
    const bf16* __restrict__ w3b, const bf16* __restrict__ hbT,
    float* __restrict__ P)
{
    int z = blockIdx.z;          // b*32 + n
    int b = z >> 5, n = z & 31;
    int bm = blockIdx.y;         // 0..7
    int tid = threadIdx.x;
    int wv = tid >> 6, lane = tid & 63;
    int q = lane >> 4, col = lane & 15;

    f32x4 acc[16];
    #pragma unroll
    for (int i = 0; i < 16; ++i) acc[i] = (f32x4){0.f, 0.f, 0.f, 0.f};

    const short8* Abase = (const short8*)(w3b + ((long)n * 512 + bm * 64 + wv * 16 + col) * 256);
    const short8* Bbase = (const short8*)(hbT + (long)b * 65536);

    #pragma unroll
    for (int kc = 0; kc < 8; ++kc) {
        short8 af = Abase[kc * 4 + q];
        #pragma unroll
        for (int nt = 0; nt < 16; ++nt) {
            short8 bfr = Bbase[(nt * 16 + col) * 32 + kc * 4 + q];
            acc[nt] = __builtin_amdgcn_mfma_f32_16x16x32_bf16(af, bfr, acc[nt], 0, 0, 0);
        }
    }

    long dbase = (long)b * 4194304 + (long)n * 256 +
                 (long)(bm * 64 + wv * 16 + q * 4) * 8192 + col;
    #pragma unroll
    for (int nt = 0; nt < 16; ++nt)
        #pragma unroll
        for (int r = 0; r < 4; ++r)
            P[dbase + (long)r * 8192 + nt * 16] = acc[nt][r];
}

// ---------------- GroupNorm: single-kernel (small) ----------------
__global__ __launch_bounds__(1024) void gn_relu_k(
    float* __restrict__ buf, const void* __restrict__ g, const void* __restrict__ bt,
    int C, int S, int groups, const int* __restrict__ flagp)
{
    int bf = *flagp;
    int nt = blockDim.x;
    int gid = blockIdx.x;
    int b = gid / groups, gr = gid % groups;
    int cpg = C / groups;
    long cnt = (long)cpg * S;
    float* base = buf + ((long)b * C + (long)gr * cpg) * S;
    double s = 0.0, s2 = 0.0;
    for (long i = threadIdx.x; i < cnt; i += nt) {
        float v = base[i];
        s += v; s2 += (double)v * v;
    }
    __shared__ double rs[1024], rq[1024];
    rs[threadIdx.x] = s; rq[threadIdx.x] = s2;
    __syncthreads();
    for (int off = nt >> 1; off > 0; off >>= 1) {
        if (threadIdx.x < off) { rs[threadIdx.x] += rs[threadIdx.x + off]; rq[threadIdx.x] += rq[threadIdx.x + off]; }
        __syncthreads();
    }
    double mean_d = rs[0] / (double)cnt;
    float mean = (float)mean_d;
    float var = (float)(rq[0] / (double)cnt - mean_d * mean_d);
    float rstd = rsqrtf(var + 1e-5f);
    for (long i = threadIdx.x; i < cnt; i += nt) {
        int c = gr * cpg + (int)(i / S);
        float v = (base[i] - mean) * rstd * ldin(g, c, bf) + ldin(bt, c, bf);
        base[i] = v > 0.f ? v : 0.f;
    }
}

// ---------------- GroupNorm: two-phase (large) ----------------
__global__ __launch_bounds__(256) void gn_part_k(
    const float* __restrict__ buf, double* __restrict__ part,
    int C, int S, int groups, int chunks)
{
    int gi = blockIdx.x / chunks, ch = blockIdx.x % chunks;
    int b = gi / groups, gr = gi % groups;
    int cpg = C / groups;
    long cnt = (long)cpg * S;
    long clen = cnt / chunks;
    const float* base = buf + ((long)b * C + (long)gr * cpg) * S + (long)ch * clen;
    double s = 0.0, s2 = 0.0;
    for (long i = threadIdx.x; i < clen; i += 256) {
        float v = base[i];
        s += v; s2 += (double)v * v;
    }
    __shared__ double rs[256], rq[256];
    rs[threadIdx.x] = s; rq[threadIdx.x] = s2;
    __syncthreads();
    for (int off = 128; off > 0; off >>= 1) {
        if (threadIdx.x < off) { rs[threadIdx.x] += rs[threadIdx.x + off]; rq[threadIdx.x] += rq[threadIdx.x + off]; }
        __syncthreads();
    }
    if (threadIdx.x == 0) { part[blockIdx.x * 2] = rs[0]; part[blockIdx.x * 2 + 1] = rq[0]; }
}

__global__ __launch_bounds__(256) void gn_apply_k(
    float* __restrict__ buf, const double* __restrict__ part,
    const void* __restrict__ g, const void* __restrict__ bt,
    int C, int S, int groups, int chunks, const int* __restrict__ flagp)
{
    int bf = *flagp;
    int gi = blockIdx.x / chunks, ch = blockIdx.x % chunks;
    int b = gi / groups, gr = gi % groups;
    int cpg = C / groups;
    long cnt = (long)cpg * S;
    long clen = cnt / chunks;
    double s = 0.0, s2 = 0.0;
    for (int k = 0; k < chunks; ++k) {
        s += part[(gi * chunks + k) * 2];
        s2 += part[(gi * chunks + k) * 2 + 1];
    }
    double mean_d = s / (double)cnt;
    float mean = (float)mean_d;
    float var = (float)(s2 / (double)cnt - mean_d * mean_d);
    float rstd = rsqrtf(var + 1e-5f);
    float* base = buf + ((long)b * C + (long)gr * cpg) * S + (long)ch * clen;
    long off0 = (long)ch * clen;
    for (long i = threadIdx.x; i < clen; i += 256) {
        int c = gr * cpg + (int)((off0 + i) / S);
        float v = (base[i] - mean) * rstd * ldin(g, c, bf) + ldin(bt, c, bf);
        base[i] = v > 0.f ? v : 0.f;
    }
}

// ---------------- sparse mask table ----------------
__global__ __launch_bounds__(384) void build_table_k(
    const void* __restrict__ mask, int* __restrict__ tabd,
    float* __restrict__ tabw, const int* __restrict__ flagp)
{
    int bf = *flagp;
    int nw = blockIdx.x;
    int w = nw >> 5, n = nw & 31;
    int tid = threadIdx.x;
    int d = tid - 165;
    float v = 0.f;
    if (d <= 165) {
        if (d < 0) v = ldin(mask, (long)(254 + d) * 65536 + ((long)n * 256 + 254) * 8 + w, bf);
        else       v = ldin(mask, (long)(1 + d) * 65536 + ((long)n * 256 + 1) * 8 + w, bf);
    }
    __shared__ unsigned char nz[384];
    nz[tid] = (v != 0.f) ? 1 : 0;
    if (tid < 6) { tabd[nw * 6 + tid] = 0; tabw[nw * 6 + tid] = 0.f; }
    __syncthreads();
    if (v != 0.f) {
        int slot = 0;
        for (int j = 0; j < tid; ++j) slot += nz[j];
        if (slot < 6) { tabd[nw * 6 + slot] = d; tabw[nw * 6 + slot] = v; }
    }
}

__global__ void build_corr_k(const void* __restrict__ mask, const int* __restrict__ tabd,
                             const float* __restrict__ tabw, float* __restrict__ corrB,
                             const int* __restrict__ flagp) {
    int bf = *flagp;
    int idx = blockIdx.x * 256 + threadIdx.x;   // 65536
    if (idx >= 65536) return;
    int n = idx >> 11, p = idx & 2047;
    int t = p >> 3, w = p & 7;
    float mv = ldin(mask, ((long)n * 256 + t) * 8 + w, bf);
    float sub = 0.f;
    int base = (w * 32 + n) * 6;
    for (int k = 0; k < 6; ++k)
        if (tabd[base + k] == -t && tabw[base + k] != 0.f) sub += tabw[base + k];
    corrB[idx] = mv - sub;
}

// partial apply: block = (h3, half); 16 n-values staged; writes part[half] (no bias)
__global__ __launch_bounds__(256) void apply_y_k(
    const float* __restrict__ P, const int* __restrict__ tabd,
    const float* __restrict__ tabw, float* __restrict__ part,
    const int* __restrict__ flagp)
{
    int bx = blockIdx.x;                 // 0..1023
    int h3 = bx >> 1, half = bx & 1;
    int n0 = half * 16;
    __shared__ float2 Pl2[16 * 256];     // 32 KB
    __shared__ float4 Tp4[384];          // 6 KB
    const float4* p04 = (const float4*)(P + ((long)h3 * 32 + n0) * 256);
    const float4* p14 = (const float4*)(P + ((long)(512 + h3) * 32 + n0) * 256);
    float4* pl4 = (float4*)Pl2;
    for (int i = threadIdx.x; i < 1024; i += 256) {
        float4 a = p04[i], b = p14[i];
        pl4[i * 2]     = make_float4(a.x, b.x, a.y, b.y);
        pl4[i * 2 + 1] = make_float4(a.z, b.z, a.w, b.w);
    }
    float2* tp2 = (float2*)Tp4;
    for (int i = threadIdx.x; i < 768; i += 256) {
        int el = i / 6, k = i - el * 6;
        int ge = ((el >> 4) << 5) + n0 + (el & 15);
        tp2[i] = make_float2(tabw[ge * 6 + k], __int_as_float(tabd[ge * 6 + k]));
    }
    __syncthreads();

    int t = threadIdx.x;
    float a0[8], a1[8];
    #pragma unroll
    for (int w = 0; w < 8; ++w) { a0[w] = 0.f; a1[w] = 0.f; }

    #pragma unroll 1
    for (int nl = 0; nl < 16; ++nl) {
        const float2* Pn = Pl2 + (nl << 8);
        #pragma unroll
        for (int w = 0; w < 8; ++w) {
            int e4 = ((w << 4) + nl) * 3;
            float4 q0 = Tp4[e4], q1 = Tp4[e4 + 1], q2 = Tp4[e4 + 2];
            float wts[6] = {q0.x, q0.z, q1.x, q1.z, q2.x, q2.z};
            int   dss[6] = {__float_as_int(q0.y), __float_as_int(q0.w),
                            __float_as_int(q1.y), __float_as_int(q1.w),
                            __float_as_int(q2.y), __float_as_int(q2.w)};
            #pragma unroll
            for (int k = 0; k < 6; ++k) {
                int tau = t + dss[k];
                int idx = tau & 255;
                float wt = ((unsigned)tau < 256u) ? wts[k] : 0.f;
                float2 pv = Pn[idx];
                a0[w] += wt * pv.x;
                a1[w] += wt * pv.y;
            }
        }
    }

    long y0 = (long)half * 2097152 + (long)h3 * 2048 + (long)t * 8;
    long y1 = y0 + 512L * 2048;
    *(float4*)(part + y0)     = make_float4(a0[0], a0[1], a0[2], a0[3]);
    *(float4*)(part + y0 + 4) = make_float4(a0[4], a0[5], a0[6], a0[7]);
    *(float4*)(part + y1)     = make_float4(a1[0], a1[1], a1[2], a1[3]);
    *(float4*)(part + y1 + 4) = make_float4(a1[4], a1[5], a1[6], a1[7]);
}

// y = part0 + part1 + r3b[h3] + sum_n P[b,h3,n,0] * corrB[n,p]   (corr fused)
__global__ void merge_y_k(const float* __restrict__ part, const float* __restrict__ P,
                          const float* __restrict__ corrB, float* __restrict__ y,
                          const void* __restrict__ r3b, const int* __restrict__ flagp) {
    int bf = *flagp;
    int i = blockIdx.x * 256 + threadIdx.x;   // 524288 float4
    if (i >= 524288) return;
    const float4* p4 = (const float4*)part;
    float4 a = p4[i], b = p4[i + 524288];
    long e = (long)i * 4;
    int bb_ = (int)(e >> 20);
    int h3 = (int)((e >> 11) & 511);
    int p = (int)(e & 2047);
    float bias = ldin(r3b, h3, bf);
    float4 acc = make_float4(a.x + b.x + bias, a.y + b.y + bias,
                             a.z + b.z + bias, a.w + b.w + bias);
    const float* p0 = P + ((long)(bb_ * 512 + h3) * 32) * 256;
    #pragma unroll 4
    for (int n = 0; n < 32; ++n) {
        float pv = p0[n * 256];
        float4 cb = *(const float4*)(corrB + n * 2048 + p);
        acc.x += pv * cb.x; acc.y += pv * cb.y;
        acc.z += pv * cb.z; acc.w += pv * cb.w;
    }
    ((float4*)y)[i] = acc;
}

__global__ __launch_bounds__(64) void head_out_k(
    const float* __restrict__ t1s, const float* __restrict__ t1e,
    const void* __restrict__ s2w, const void* __restrict__ s2b,
    const void* __restrict__ e2w, const void* __restrict__ e2b,
    void* __restrict__ out, const int* __restrict__ flagp) {
    int bf = *flagp;
    int idx = blockIdx.x * 64 + threadIdx.x;   // 4096
    if (idx >= 4096) return;
    int b = idx >> 11, p = idx & 2047;
    const float* ts = t1s + (long)b * 262144 + p;
    const float* te = t1e + (long)b * 262144 + p;
    float as = ldin(s2b, 0, bf), ae = ldin(e2b, 0, bf);
    #pragma unroll 8
    for (int c = 0; c < 128; ++c) {
        as += ldin(s2w, c, bf) * ts[(long)c * 2048];
        ae += ldin(e2w, c, bf) * te[(long)c * 2048];
    }
    float vs = 1.f / (1.f + expf(-as));
    float ve = 1.f / (1.f + expf(-ae));
    long o0 = ((long)b * 2) * 2048 + p;
    long o1 = ((long)b * 2 + 1) * 2048 + p;
    if (bf) {
        ((bf16*)out)[o0] = __float2bfloat16(vs);
        ((bf16*)out)[o1] = __float2bfloat16(ve);
    } else {
        ((float*)out)[o0] = vs;
        ((float*)out)[o1] = ve;
    }
}

// ---------------- launch ----------------
extern "C" void kernel_launch(void* const* d_in, const int* in_sizes, int n_in,
                              void* d_out, int out_size, void* d_ws, size_t ws_size,
                              hipStream_t stream) {
    const void* x    = d_in[0];
    const void* mask = d_in[1];
    const void* c1w  = d_in[2];
    const void* c1b  = d_in[3];
    const void* gn1g = d_in[4];
    const void* gn1b = d_in[5];
    const void* w3   = d_in[6];
    const void* r3b  = d_in[7];
    const void* gn3g = d_in[8];
    const void* gn3b = d_in[9];
    const void* w2   = d_in[10];
    const void* r2b  = d_in[11];
    const void* gn2g = d_in[12];
    const void* gn2b = d_in[13];
    const void* s1w  = d_in[14];
    const void* s1b  = d_in[15];
    const void* sgng = d_in[16];
    const void* sgnb = d_in[17];
    const void* s2w  = d_in[18];
    const void* s2b  = d_in[19];
    const void* e1w  = d_in[20];
    const void* e1b  = d_in[21];
    const void* egng = d_in[22];
    const void* egnb = d_in[23];
    const void* e2w  = d_in[24];
    const void* e2b  = d_in[25];
    float* ws = (float*)d_ws;

    int*   flagI = (int*)(ws + 0);       // 64 reserved
    float* h     = ws + 64;              // 131072
    float* c1t   = ws + 131136;          // 393216 (c1wb bf16)
    float* w2t   = ws + 524352;          // 65536 (w2b bf16)
    float* s1t   = ws + 589888;          // 294912 (s1wb+e1wb bf16)
    float* corrB = ws + 884800;          // 65536
    float* tabw  = ws + 950336;          // 1536
    int*   tabd  = (int*)(ws + 951872);  // 1536
    float* t1s   = ws + 986176;          // 524288
    float* t1e   = ws + 1510464;         // 524288
    float* f     = ws + 2034752;         // 524288
    float* y     = ws + 2559040;         // 2097152
    float* w3reg = ws + 4656192;         // 4194304 (bf16 bufs / apply partials)
    float* Pb    = ws + 8850496;         // 8388608
    double* gnbuf = (double*)(ws + 17239104); // 1024 doubles
    bf16*  w3b   = (bf16*)w3reg;
    bf16*  hbT   = (bf16*)(w3reg + 2097152);
    bf16*  c1wb  = (bf16*)c1t;
    bf16*  w2b   = (bf16*)w2t;
    bf16*  hwb   = (bf16*)s1t;
    bf16*  colxb = (bf16*)y;                       // y dead until merge
    bf16*  fcolb = (bf16*)Pb;                      // Pb[0..2.36M floats) post-merge
    bf16*  yT    = (bf16*)(Pb + 4194304);          // Pb tail (P dead post-merge)
    float* ypart = w3reg;                          // 4M floats (w3b/hbT dead post-pgemm)

    dim3 blk(256);
    dim3 blkG(1024);

    detect_k<<<dim3(1), blk, 0, stream>>>((const unsigned short*)x, flagI);

    // weight prep + table extraction
    cast_bf_k<<<dim3(1536), blk, 0, stream>>>(c1w, c1wb, 393216, flagI);
    cast_bf_k<<<dim3(576),  blk, 0, stream>>>(s1w, hwb, 147456, flagI);
    cast_bf_k<<<dim3(576),  blk, 0, stream>>>(e1w, hwb + 147456, 147456, flagI);
    cast_bf_k<<<dim3(256),  blk, 0, stream>>>(w2, w2b, 65536, flagI);
    transpose_w3b_k<<<dim3(512), blk, 0, stream>>>(w3, w3b, flagI);
    build_table_k<<<dim3(256), dim3(384), 0, stream>>>(mask, tabd, tabw, flagI);
    build_corr_k<<<dim3(256), blk, 0, stream>>>(mask, tabd, tabw, corrB, flagI);

    // conv1 via MFMA + GN1 + ReLU
    im2col_xb_k<<<dim3(3072), blk, 0, stream>>>(x, colxb, flagI);
    wgemm_mfma<1><<<dim3(16, 4, 2), blk, 0, stream>>>(
        c1wb, colxb, h, c1b, c1b, 256, 1536, 256, 1, 0L, flagI);
    gn_relu_k<<<dim3(64), blkG, 0, stream>>>(h, gn1g, gn1b, 256, 256, 32, flagI);

    // P-GEMM via bf16 MFMA
    cast_hT_k<<<dim3(512), blk, 0, stream>>>(h, hbT);
    pgemm_mfma<<<dim3(1, 8, 64), blk, 0, stream>>>(w3b, hbT, Pb);

    // sparse mask apply + fused merge(bias + corr) + GN3 (2-phase)
    apply_y_k<<<dim3(1024), blk, 0, stream>>>(Pb, tabd, tabw, ypart, flagI);
    merge_y_k<<<dim3(2048), blk, 0, stream>>>(ypart, Pb, corrB, y, r3b, flagI);
    gn_part_k<<<dim3(512), blk, 0, stream>>>(y, gnbuf, 512, 2048, 32, 8);
    gn_apply_k<<<dim3(512), blk, 0, stream>>>(y, gnbuf, gn3g, gn3b, 512, 2048, 32, 8, flagI);

    // r2d via MFMA: cast-transpose y -> yT bf16, wgemm (bias fused) + GN2 (2-phase)
    castT_k<<<dim3(32, 8, 2), blk, 0, stream>>>(y, yT);
    wgemm_mfma<2><<<dim3(64, 2, 2), blk, 0, stream>>>(
        w2b, yT, f, r2b, r2b, 128, 512, 2048, 2, 0L, flagI);
    gn_part_k<<<dim3(256), blk, 0, stream>>>(f, gnbuf, 128, 2048, 32, 4);
    gn_apply_k<<<dim3(256), blk, 0, stream>>>(f, gnbuf, gn2g, gn2b, 128, 2048, 32, 4, flagI);

    // heads via MFMA + GN (2-phase each)
    im2col_fb_k<<<dim3(18432), blk, 0, stream>>>(f, fcolb);
    wgemm_mfma<4><<<dim3(32, 2, 4), blk, 0, stream>>>(
        hwb, fcolb, t1s, s1b, e1b, 128, 1152, 2048, 2, 147456L, flagI);
    gn_part_k<<<dim3(256), blk, 0, stream>>>(t1s, gnbuf, 128, 2048, 32, 4);
    gn_apply_k<<<dim3(256), blk, 0, stream>>>(t1s, gnbuf, sgng, sgnb, 128, 2048, 32, 4, flagI);
    gn_part_k<<<dim3(256), blk, 0, stream>>>(t1e, gnbuf, 128, 2048, 32, 4);
    gn_apply_k<<<dim3(256), blk, 0, stream>>>(t1e, gnbuf, egng, egnb, 128, 2048, 32, 4, flagI);

    // 1x1 head convs + sigmoid -> output
    head_out_k<<<dim3(64), dim3(64), 0, stream>>>(t1s, t1e, s2w, s2b, e2w, e2b, d_out, flagI);
}